// Round 9
// baseline (370.204 us; speedup 1.0000x reference)
//
#include <hip/hip_runtime.h>
#include <hip/hip_fp16.h>
#include <cstdint>
#include <cmath>

// GCN, 4 layers. Structure: A(hW) = (Ah)W with norm folded into features:
//   g = dis (.) h  stored FP16 (halves the dominant gather traffic),
//   A_norm h [d] = dis[d] * ( sum_e w_e * g[src_e] + g[d] )
// CSR built once per call (atomic hist w/ rank capture -> scan -> atomic-free
// scatter).
// R8 post-mortem: hist is pinned at ~23 G atomics/s across ILP 1..8 and
// occupancy 18..63% -> device-scope returning-atomic throughput wall
// (memory-side RMW); left as-is.
// R9: aggregate inner loop rebuilt -- cooperative pairs prefetch (lane q of
// each 8-lane group loads pairs[j+q], one coalesced 512B instr per 8 edges,
// redistribution via __shfl) + 8 row-gathers in flight. VMEM instrs per
// 8 edges: 16 -> 9; MLP 4 -> 8.

// ---------------------------------------------------------------- setup

__global__ __launch_bounds__(256) void init_kernel(int* __restrict__ cnt, int n) {
    int i = blockIdx.x * 256 + threadIdx.x;
    if (i < n) cnt[i] = 0;
}

// count edges per destination; atomic return = rank of edge within its row.
__global__ __launch_bounds__(256) void hist_kernel(const int* __restrict__ dst,
                                                   int* __restrict__ cnt,
                                                   int* __restrict__ rank, int E) {
    int t = blockIdx.x * 2048 + threadIdx.x;
    if (t + 1792 < E) {
        int d[8];
        #pragma unroll
        for (int u = 0; u < 8; ++u) d[u] = dst[t + u * 256];
        int r[8];
        #pragma unroll
        for (int u = 0; u < 8; ++u) r[u] = atomicAdd(&cnt[d[u]], 1);
        #pragma unroll
        for (int u = 0; u < 8; ++u) rank[t + u * 256] = r[u];
    } else {
        #pragma unroll
        for (int u = 0; u < 8; ++u) {
            int e = t + u * 256;
            if (e < E) rank[e] = atomicAdd(&cnt[dst[e]], 1);
        }
    }
}

// ------------------------------------------------- device-wide scan (3 kernels)

__global__ __launch_bounds__(256) void scan_block_kernel(const int* __restrict__ cnt,
                                                         int* __restrict__ offsets,
                                                         int* __restrict__ bsum, int n) {
    __shared__ int wtot[4];
    int t = threadIdx.x;
    int i = blockIdx.x * 1024 + t * 4;
    int4 v = make_int4(0, 0, 0, 0);
    if (i + 3 < n) v = *reinterpret_cast<const int4*>(cnt + i);
    else {
        if (i     < n) v.x = cnt[i];
        if (i + 1 < n) v.y = cnt[i + 1];
        if (i + 2 < n) v.z = cnt[i + 2];
        if (i + 3 < n) v.w = cnt[i + 3];
    }
    int tsum = v.x + v.y + v.z + v.w;
    int lane = t & 63, wid = t >> 6;
    int x = tsum;
    #pragma unroll
    for (int off = 1; off < 64; off <<= 1) {
        int tt = __shfl_up(x, off);
        if (lane >= off) x += tt;
    }
    if (lane == 63) wtot[wid] = x;
    __syncthreads();
    int wbase = 0;
    #pragma unroll
    for (int wv = 0; wv < 4; ++wv) if (wv < wid) wbase += wtot[wv];
    int e0 = wbase + x - tsum;
    int4 o;
    o.x = e0; o.y = e0 + v.x; o.z = o.y + v.y; o.w = o.z + v.z;
    if (i + 3 < n) *reinterpret_cast<int4*>(offsets + i) = o;
    else {
        if (i     < n) offsets[i]     = o.x;
        if (i + 1 < n) offsets[i + 1] = o.y;
        if (i + 2 < n) offsets[i + 2] = o.z;
        if (i + 3 < n) offsets[i + 3] = o.w;
    }
    if (t == 255) bsum[blockIdx.x] = wbase + x;
}

__global__ __launch_bounds__(64) void scan_bsum_kernel(int* __restrict__ bsum, int B) {
    int lane = threadIdx.x;
    int run = 0;
    for (int base = 0; base < B; base += 64) {
        int i = base + lane;
        int v = (i < B) ? bsum[i] : 0;
        int x = v;
        #pragma unroll
        for (int off = 1; off < 64; off <<= 1) {
            int t = __shfl_up(x, off);
            if (lane >= off) x += t;
        }
        if (i < B) bsum[i] = run + x - v;
        run += __shfl(x, 63);
    }
}

__global__ __launch_bounds__(256) void scan_add_kernel(int* __restrict__ offsets,
                                                       const int* __restrict__ bsum,
                                                       int n, int E) {
    int base = bsum[blockIdx.x];
    int i = blockIdx.x * 1024 + threadIdx.x * 4;
    if (i + 3 < n) {
        int4 o = *reinterpret_cast<int4*>(offsets + i);
        o.x += base; o.y += base; o.z += base; o.w += base;
        *reinterpret_cast<int4*>(offsets + i) = o;
    } else {
        for (int k = 0; k < 4; ++k) if (i + k < n) offsets[i + k] += base;
    }
    if (blockIdx.x == 0 && threadIdx.x == 0) offsets[n] = E;
}

// scatter, atomic-free: pairs[offsets[dst]+rank] = (src, raw weight). ILP-4.
__global__ __launch_bounds__(256) void scatter_kernel(const int* __restrict__ src,
                                                      const int* __restrict__ dst,
                                                      const float* __restrict__ w,
                                                      const int* __restrict__ rank,
                                                      const int* __restrict__ offsets,
                                                      int2* __restrict__ pairs, int E) {
    int t = blockIdx.x * 1024 + threadIdx.x;
    if (t + 768 < E) {
        int d[4], s[4], r[4]; float wv[4];
        #pragma unroll
        for (int u = 0; u < 4; ++u) {
            int e = t + u * 256;
            d[u] = dst[e]; s[u] = src[e]; wv[u] = w[e]; r[u] = rank[e];
        }
        int o[4];
        #pragma unroll
        for (int u = 0; u < 4; ++u) o[u] = offsets[d[u]];
        #pragma unroll
        for (int u = 0; u < 4; ++u)
            pairs[o[u] + r[u]] = make_int2(s[u], __float_as_int(wv[u]));
    } else {
        #pragma unroll
        for (int u = 0; u < 4; ++u) {
            int e = t + u * 256;
            if (e < E)
                pairs[offsets[dst[e]] + rank[e]] = make_int2(src[e], __float_as_int(w[e]));
        }
    }
}

// deg = 1 + row-sum of w; dis = rsqrt(deg). 16-lane group per node.
__global__ __launch_bounds__(256) void rowsum_dis_kernel(const int* __restrict__ offsets,
                                                         const int2* __restrict__ pairs,
                                                         float* __restrict__ dis, int n) {
    int node = blockIdx.x * 16 + (threadIdx.x >> 4);
    int q = threadIdx.x & 15;
    if (node >= n) return;
    int j0 = offsets[node], end = offsets[node + 1];
    float s = 0.f;
    for (int j = j0 + q; j < end; j += 16) s += __int_as_float(pairs[j].y);
    #pragma unroll
    for (int off = 8; off; off >>= 1) s += __shfl_xor(s, off);
    if (q == 0) dis[node] = rsqrtf(1.0f + s);
}

// g0 = fp16( dis (.) x ); one thread per 8 features
__global__ __launch_bounds__(256) void scale_kernel(const float* __restrict__ x,
                                                    const float* __restrict__ dis,
                                                    __half* __restrict__ g, int n) {
    int i = blockIdx.x * 256 + threadIdx.x;          // 8-float unit index
    if (i >= n * 8) return;
    float d = dis[i >> 3];
    float4 a = reinterpret_cast<const float4*>(x)[i * 2];
    float4 b = reinterpret_cast<const float4*>(x)[i * 2 + 1];
    __half2 h[4];
    h[0] = __float22half2_rn(make_float2(d * a.x, d * a.y));
    h[1] = __float22half2_rn(make_float2(d * a.z, d * a.w));
    h[2] = __float22half2_rn(make_float2(d * b.x, d * b.y));
    h[3] = __float22half2_rn(make_float2(d * b.z, d * b.w));
    reinterpret_cast<float4*>(g)[i] = *reinterpret_cast<float4*>(h);
}

// --------------------------------------- aggregation: agg[d] = dis[d]*(sum w*g[s] + g[d])
// 8-lane group per node (8 nodes/wave); lane q owns half8 #q (features 8q..8q+7).
// R9: per 8-edge chunk, ONE cooperative pairs load (lane q reads pairs[j+q],
// 512B coalesced per wave) + __shfl redistribution + 8 independent row-gathers.
__device__ __forceinline__ void accum8(float* acc, float4 rv, float w) {
    const __half2* h = reinterpret_cast<const __half2*>(&rv);
    #pragma unroll
    for (int k = 0; k < 4; ++k) {
        float2 f = __half22float2(h[k]);
        acc[2 * k]     = fmaf(w, f.x, acc[2 * k]);
        acc[2 * k + 1] = fmaf(w, f.y, acc[2 * k + 1]);
    }
}

__global__ __launch_bounds__(256) void aggregate_kernel(const __half* __restrict__ g,
                                                        const float* __restrict__ dis,
                                                        const int* __restrict__ offsets,
                                                        const int2* __restrict__ pairs,
                                                        __half* __restrict__ aggout, int n) {
    int lane  = threadIdx.x & 63;
    int node  = blockIdx.x * 32 + (threadIdx.x >> 3);
    int q     = lane & 7;         // half8 slot within row
    int gbase = lane & 56;        // first lane of this 8-lane group
    if (node >= n) return;
    const float4* gt = reinterpret_cast<const float4*>(g);   // row = 8 x float4 (128B)

    float acc[8] = {0.f, 0.f, 0.f, 0.f, 0.f, 0.f, 0.f, 0.f};
    int j   = offsets[node];
    int end = offsets[node + 1];

    // full 8-edge chunks
    for (; j + 8 <= end; j += 8) {
        int2 myp = pairs[j + q];                 // cooperative: 8 edges per group
        int   sk[8];
        float wk[8];
        #pragma unroll
        for (int k = 0; k < 8; ++k) {
            sk[k] = __shfl(myp.x, gbase + k);
            wk[k] = __int_as_float(__shfl(myp.y, gbase + k));
        }
        float4 r[8];
        #pragma unroll
        for (int k = 0; k < 8; ++k) r[k] = gt[(size_t)sk[k] * 8 + q];
        #pragma unroll
        for (int k = 0; k < 8; ++k) accum8(acc, r[k], wk[k]);
    }
    // remainder (<8): one clamped cooperative load + guarded gathers
    if (j < end) {
        int m = end - j;                          // 1..7, uniform within group
        int idx = j + q; if (idx >= end) idx = end - 1;
        int2 myp = pairs[idx];
        int   sk[8];
        float wk[8];
        #pragma unroll
        for (int k = 0; k < 8; ++k) {
            sk[k] = __shfl(myp.x, gbase + k);     // shuffles outside the guard:
            wk[k] = __int_as_float(__shfl(myp.y, gbase + k)); // values pre-written by all lanes
        }
        #pragma unroll
        for (int k = 0; k < 8; ++k) {
            if (k < m) {
                float4 r = gt[(size_t)sk[k] * 8 + q];
                accum8(acc, r, wk[k]);
            }
        }
    }

    // self term (weight 1)
    float4 rs = gt[(size_t)node * 8 + q];
    accum8(acc, rs, 1.0f);

    float dn = dis[node];
    __half2 o[4];
    o[0] = __float22half2_rn(make_float2(dn * acc[0], dn * acc[1]));
    o[1] = __float22half2_rn(make_float2(dn * acc[2], dn * acc[3]));
    o[2] = __float22half2_rn(make_float2(dn * acc[4], dn * acc[5]));
    o[3] = __float22half2_rn(make_float2(dn * acc[6], dn * acc[7]));
    reinterpret_cast<float4*>(aggout)[(size_t)node * 8 + q] = *reinterpret_cast<float4*>(o);
}

// ---- helper: load a 64-wide fp16 row into 64 fp32 registers (8x float4 loads)
__device__ __forceinline__ void load_row64(const __half* __restrict__ in, int row,
                                           float* __restrict__ h) {
    const float4* inp = reinterpret_cast<const float4*>(in + (size_t)row * 64);
    #pragma unroll
    for (int i = 0; i < 8; ++i) {
        float4 raw = inp[i];
        const __half2* hp = reinterpret_cast<const __half2*>(&raw);
        #pragma unroll
        for (int k = 0; k < 4; ++k) {
            float2 f = __half22float2(hp[k]);
            h[i * 8 + 2 * k]     = f.x;
            h[i * 8 + 2 * k + 1] = f.y;
        }
    }
}

// ------------------------------------------- GEMM 64x64 + bias + ELU + dis-scale -> fp16
// g_next_row = fp16( dis[row] * elu(in_row @ W + b) )
__global__ __launch_bounds__(256) void gemm64_kernel(const __half* __restrict__ in,
                                                     const float* __restrict__ W,
                                                     const float* __restrict__ b,
                                                     const float* __restrict__ dis,
                                                     __half* __restrict__ out, int n) {
    __shared__ float WT[64][64];   // WT[c][k] = W[k][c]
    for (int idx = threadIdx.x; idx < 64 * 64; idx += 256) {
        int k = idx >> 6, c = idx & 63;
        WT[c][k] = W[idx];
    }
    __syncthreads();

    int row = blockIdx.x * 256 + threadIdx.x;
    if (row >= n) return;

    float h[64];
    load_row64(in, row, h);

    float dn = dis[row];
    __half* outp = out + (size_t)row * 64;
    #pragma unroll 2
    for (int c4 = 0; c4 < 16; ++c4) {
        float4 bv = *reinterpret_cast<const float4*>(b + c4 * 4);
        float r[4];
        #pragma unroll
        for (int cc = 0; cc < 4; ++cc) {
            const float4* wt = reinterpret_cast<const float4*>(&WT[c4 * 4 + cc][0]);
            float4 a = make_float4(0.f, 0.f, 0.f, 0.f);
            #pragma unroll
            for (int i = 0; i < 16; ++i) {
                float4 w4 = wt[i];
                a.x = fmaf(h[4 * i],     w4.x, a.x);
                a.y = fmaf(h[4 * i + 1], w4.y, a.y);
                a.z = fmaf(h[4 * i + 2], w4.z, a.z);
                a.w = fmaf(h[4 * i + 3], w4.w, a.w);
            }
            float v = (a.x + a.y) + (a.z + a.w) + ((const float*)&bv)[cc];
            v = (v > 0.f) ? v : expm1f(v);      // ELU
            r[cc] = dn * v;                     // pre-scale for next aggregate
        }
        __half2 pk[2];
        pk[0] = __float22half2_rn(make_float2(r[0], r[1]));
        pk[1] = __float22half2_rn(make_float2(r[2], r[3]));
        *reinterpret_cast<float2*>(outp + c4 * 4) = *reinterpret_cast<float2*>(pk);
    }
}

// ------------------------------- GEMM 64x40 + bias + fused row log_softmax -> d_out
__global__ __launch_bounds__(256) void gemm40_softmax_kernel(const __half* __restrict__ in,
                                                             const float* __restrict__ W,
                                                             const float* __restrict__ b,
                                                             float* __restrict__ out, int n) {
    __shared__ float WT[40][64];   // WT[c][k] = W[k][c]
    for (int idx = threadIdx.x; idx < 64 * 40; idx += 256) {
        int k = idx / 40, c = idx % 40;
        WT[c][k] = W[idx];
    }
    __syncthreads();

    int row = blockIdx.x * 256 + threadIdx.x;
    if (row >= n) return;

    float h[64];
    load_row64(in, row, h);

    float r[40];
    #pragma unroll 2
    for (int c = 0; c < 40; ++c) {
        const float4* wt = reinterpret_cast<const float4*>(&WT[c][0]);
        float4 a = make_float4(0.f, 0.f, 0.f, 0.f);
        #pragma unroll
        for (int i = 0; i < 16; ++i) {
            float4 w4 = wt[i];
            a.x = fmaf(h[4 * i],     w4.x, a.x);
            a.y = fmaf(h[4 * i + 1], w4.y, a.y);
            a.z = fmaf(h[4 * i + 2], w4.z, a.z);
            a.w = fmaf(h[4 * i + 3], w4.w, a.w);
        }
        r[c] = (a.x + a.y) + (a.z + a.w) + b[c];
    }

    float m = r[0];
    #pragma unroll
    for (int c = 1; c < 40; ++c) m = fmaxf(m, r[c]);
    float s = 0.f;
    #pragma unroll
    for (int c = 0; c < 40; ++c) s += expf(r[c] - m);
    float ls = logf(s) + m;

    float* outp = out + (size_t)row * 40;
    #pragma unroll
    for (int c4 = 0; c4 < 10; ++c4) {
        *reinterpret_cast<float4*>(outp + c4 * 4) =
            make_float4(r[c4 * 4] - ls, r[c4 * 4 + 1] - ls,
                        r[c4 * 4 + 2] - ls, r[c4 * 4 + 3] - ls);
    }
}

// ---------------------------------------------------------------- launch

static inline size_t align_up(size_t x, size_t a) { return (x + a - 1) & ~(a - 1); }

extern "C" void kernel_launch(void* const* d_in, const int* in_sizes, int n_in,
                              void* d_out, int out_size, void* d_ws, size_t ws_size,
                              hipStream_t stream) {
    const float* x  = (const float*)d_in[0];
    const int*   ei = (const int*)d_in[1];     // [2][E] flat: src then dst
    const float* ea = (const float*)d_in[2];
    const float* W1 = (const float*)d_in[3];
    const float* b1 = (const float*)d_in[4];
    const float* W2 = (const float*)d_in[5];
    const float* b2 = (const float*)d_in[6];
    const float* W3 = (const float*)d_in[7];
    const float* b3 = (const float*)d_in[8];
    const float* W4 = (const float*)d_in[9];
    const float* b4 = (const float*)d_in[10];

    const int N = in_sizes[0] / 64;
    const int E = in_sizes[1] / 2;

    const int* src = ei;
    const int* dst = ei + E;

    const int B = (N + 1023) / 1024;

    // workspace carve-up
    char* p = (char*)d_ws;
    int*    cnt     = (int*)p;    p += align_up((size_t)N * 4, 256);
    int*    offsets = (int*)p;    p += align_up(((size_t)N + 1) * 4, 256);
    int*    bsum    = (int*)p;    p += align_up(((size_t)B + 1) * 4, 256);
    float*  dis     = (float*)p;  p += align_up((size_t)N * 4, 256);
    int2*   pairs   = (int2*)p;   p += align_up(((size_t)E + 8) * 8, 256);
    __half* gA      = (__half*)p; p += align_up((size_t)N * 64 * 2, 256);  // fp16 features
    __half* gB      = (__half*)p; p += align_up((size_t)N * 64 * 2, 256);  // fp16 aggregate
    int*    rank    = (int*)gB;   // aliases gB: dead before layer-1 aggregate writes gB
    (void)ws_size;

    const int nb_n   = (N + 255) / 256;
    const int nb_h   = (E + 2047) / 2048;       // hist ILP-8
    const int nb_sc  = (E + 1023) / 1024;       // scatter ILP-4
    const int nb_g16 = (N + 15) / 16;           // 16-lane-group kernels
    const int nb_g8  = (N + 31) / 32;           // 8-lane-group aggregate
    const int nb_s   = ((size_t)N * 8 + 255) / 256;

    // --- graph preprocessing ---
    init_kernel<<<nb_n, 256, 0, stream>>>(cnt, N);
    hist_kernel<<<nb_h, 256, 0, stream>>>(dst, cnt, rank, E);
    scan_block_kernel<<<B, 256, 0, stream>>>(cnt, offsets, bsum, N);
    scan_bsum_kernel<<<1, 64, 0, stream>>>(bsum, B);
    scan_add_kernel<<<B, 256, 0, stream>>>(offsets, bsum, N, E);
    scatter_kernel<<<nb_sc, 256, 0, stream>>>(src, dst, ea, rank, offsets, pairs, E);
    rowsum_dis_kernel<<<nb_g16, 256, 0, stream>>>(offsets, pairs, dis, N);

    // --- g0 = fp16(dis (.) x) ---
    scale_kernel<<<nb_s, 256, 0, stream>>>(x, dis, gA, N);

    // --- layer 1 ---
    aggregate_kernel<<<nb_g8, 256, 0, stream>>>(gA, dis, offsets, pairs, gB, N);
    gemm64_kernel<<<nb_n, 256, 0, stream>>>(gB, W1, b1, dis, gA, N);
    // --- layer 2 ---
    aggregate_kernel<<<nb_g8, 256, 0, stream>>>(gA, dis, offsets, pairs, gB, N);
    gemm64_kernel<<<nb_n, 256, 0, stream>>>(gB, W2, b2, dis, gA, N);
    // --- layer 3 ---
    aggregate_kernel<<<nb_g8, 256, 0, stream>>>(gA, dis, offsets, pairs, gB, N);
    gemm64_kernel<<<nb_n, 256, 0, stream>>>(gB, W3, b3, dis, gA, N);
    // --- layer 4: aggregate then GEMM40 + log_softmax -> d_out ---
    aggregate_kernel<<<nb_g8, 256, 0, stream>>>(gA, dis, offsets, pairs, gB, N);
    gemm40_softmax_kernel<<<nb_n, 256, 0, stream>>>(gB, W4, b4, (float*)d_out, N);
}

// Round 10
// 327.319 us; speedup vs baseline: 1.1310x; 1.1310x over previous
//
#include <hip/hip_runtime.h>
#include <hip/hip_fp16.h>
#include <cstdint>
#include <cmath>

// GCN, 4 layers. Structure: A(hW) = (Ah)W with norm folded into features:
//   g = dis (.) h  stored FP16,
//   A_norm h [d] = dis[d] * ( sum_e w_e * g[src_e] + g[d] )
// CSR built once per call (atomic hist w/ rank capture -> scan -> atomic-free
// scatter).
// R9 post-mortem: cooperative pairs-prefetch + shfl redistribution REGRESSED
// (353->370); pairs loads were never the bottleneck. Reverted to R8 gather loop.
// R10: fusion round. aggregate+GEMM64 fused per layer via LDS row handoff
// (fp32 rows, stride 66; phase2 row->regs + wave-uniform WT reads), killing
// 3x 25.6MB gB roundtrips + 3 dispatches; rowsum_dis+scale fused. 17->12
// dispatches. hist left alone (device returning-atomic wall, ~23 G/s across
// ILP 1..8 and occupancy 18..63%).

// ---------------------------------------------------------------- setup

__global__ __launch_bounds__(256) void init_kernel(int* __restrict__ cnt, int n) {
    int i = blockIdx.x * 256 + threadIdx.x;
    if (i < n) cnt[i] = 0;
}

// count edges per destination; atomic return = rank of edge within its row.
__global__ __launch_bounds__(256) void hist_kernel(const int* __restrict__ dst,
                                                   int* __restrict__ cnt,
                                                   int* __restrict__ rank, int E) {
    int t = blockIdx.x * 2048 + threadIdx.x;
    if (t + 1792 < E) {
        int d[8];
        #pragma unroll
        for (int u = 0; u < 8; ++u) d[u] = dst[t + u * 256];
        int r[8];
        #pragma unroll
        for (int u = 0; u < 8; ++u) r[u] = atomicAdd(&cnt[d[u]], 1);
        #pragma unroll
        for (int u = 0; u < 8; ++u) rank[t + u * 256] = r[u];
    } else {
        #pragma unroll
        for (int u = 0; u < 8; ++u) {
            int e = t + u * 256;
            if (e < E) rank[e] = atomicAdd(&cnt[dst[e]], 1);
        }
    }
}

// ------------------------------------------------- device-wide scan (3 kernels)

__global__ __launch_bounds__(256) void scan_block_kernel(const int* __restrict__ cnt,
                                                         int* __restrict__ offsets,
                                                         int* __restrict__ bsum, int n) {
    __shared__ int wtot[4];
    int t = threadIdx.x;
    int i = blockIdx.x * 1024 + t * 4;
    int4 v = make_int4(0, 0, 0, 0);
    if (i + 3 < n) v = *reinterpret_cast<const int4*>(cnt + i);
    else {
        if (i     < n) v.x = cnt[i];
        if (i + 1 < n) v.y = cnt[i + 1];
        if (i + 2 < n) v.z = cnt[i + 2];
        if (i + 3 < n) v.w = cnt[i + 3];
    }
    int tsum = v.x + v.y + v.z + v.w;
    int lane = t & 63, wid = t >> 6;
    int x = tsum;
    #pragma unroll
    for (int off = 1; off < 64; off <<= 1) {
        int tt = __shfl_up(x, off);
        if (lane >= off) x += tt;
    }
    if (lane == 63) wtot[wid] = x;
    __syncthreads();
    int wbase = 0;
    #pragma unroll
    for (int wv = 0; wv < 4; ++wv) if (wv < wid) wbase += wtot[wv];
    int e0 = wbase + x - tsum;
    int4 o;
    o.x = e0; o.y = e0 + v.x; o.z = o.y + v.y; o.w = o.z + v.z;
    if (i + 3 < n) *reinterpret_cast<int4*>(offsets + i) = o;
    else {
        if (i     < n) offsets[i]     = o.x;
        if (i + 1 < n) offsets[i + 1] = o.y;
        if (i + 2 < n) offsets[i + 2] = o.z;
        if (i + 3 < n) offsets[i + 3] = o.w;
    }
    if (t == 255) bsum[blockIdx.x] = wbase + x;
}

__global__ __launch_bounds__(64) void scan_bsum_kernel(int* __restrict__ bsum, int B) {
    int lane = threadIdx.x;
    int run = 0;
    for (int base = 0; base < B; base += 64) {
        int i = base + lane;
        int v = (i < B) ? bsum[i] : 0;
        int x = v;
        #pragma unroll
        for (int off = 1; off < 64; off <<= 1) {
            int t = __shfl_up(x, off);
            if (lane >= off) x += t;
        }
        if (i < B) bsum[i] = run + x - v;
        run += __shfl(x, 63);
    }
}

__global__ __launch_bounds__(256) void scan_add_kernel(int* __restrict__ offsets,
                                                       const int* __restrict__ bsum,
                                                       int n, int E) {
    int base = bsum[blockIdx.x];
    int i = blockIdx.x * 1024 + threadIdx.x * 4;
    if (i + 3 < n) {
        int4 o = *reinterpret_cast<int4*>(offsets + i);
        o.x += base; o.y += base; o.z += base; o.w += base;
        *reinterpret_cast<int4*>(offsets + i) = o;
    } else {
        for (int k = 0; k < 4; ++k) if (i + k < n) offsets[i + k] += base;
    }
    if (blockIdx.x == 0 && threadIdx.x == 0) offsets[n] = E;
}

// scatter, atomic-free: pairs[offsets[dst]+rank] = (src, raw weight). ILP-4.
__global__ __launch_bounds__(256) void scatter_kernel(const int* __restrict__ src,
                                                      const int* __restrict__ dst,
                                                      const float* __restrict__ w,
                                                      const int* __restrict__ rank,
                                                      const int* __restrict__ offsets,
                                                      int2* __restrict__ pairs, int E) {
    int t = blockIdx.x * 1024 + threadIdx.x;
    if (t + 768 < E) {
        int d[4], s[4], r[4]; float wv[4];
        #pragma unroll
        for (int u = 0; u < 4; ++u) {
            int e = t + u * 256;
            d[u] = dst[e]; s[u] = src[e]; wv[u] = w[e]; r[u] = rank[e];
        }
        int o[4];
        #pragma unroll
        for (int u = 0; u < 4; ++u) o[u] = offsets[d[u]];
        #pragma unroll
        for (int u = 0; u < 4; ++u)
            pairs[o[u] + r[u]] = make_int2(s[u], __float_as_int(wv[u]));
    } else {
        #pragma unroll
        for (int u = 0; u < 4; ++u) {
            int e = t + u * 256;
            if (e < E)
                pairs[offsets[dst[e]] + rank[e]] = make_int2(src[e], __float_as_int(w[e]));
        }
    }
}

// fused: deg row-sum -> dis -> g0 = fp16(dis (.) x). 16 lanes per node.
__global__ __launch_bounds__(256) void rowsum_scale_kernel(const int* __restrict__ offsets,
                                                           const int2* __restrict__ pairs,
                                                           const float* __restrict__ x,
                                                           float* __restrict__ dis,
                                                           __half* __restrict__ g, int n) {
    int node = blockIdx.x * 16 + (threadIdx.x >> 4);
    int q = threadIdx.x & 15;
    if (node >= n) return;
    int j0 = offsets[node], end = offsets[node + 1];
    float s = 0.f;
    for (int j = j0 + q; j < end; j += 16) s += __int_as_float(pairs[j].y);
    #pragma unroll
    for (int off = 8; off; off >>= 1) s += __shfl_xor(s, off);
    float dn = rsqrtf(1.0f + s);
    if (q == 0) dis[node] = dn;
    float4 v = reinterpret_cast<const float4*>(x)[(size_t)node * 16 + q];
    __half2 pk[2];
    pk[0] = __float22half2_rn(make_float2(dn * v.x, dn * v.y));
    pk[1] = __float22half2_rn(make_float2(dn * v.z, dn * v.w));
    reinterpret_cast<float2*>(g + (size_t)node * 64)[q] = *reinterpret_cast<float2*>(pk);
}

// ---------------------------------------------------------------- aggregation core
// 8-lane group per node; lane q owns half8 #q (features 8q..8q+7). fp32 accum.
__device__ __forceinline__ void accum8(float* acc, float4 rv, float w) {
    const __half2* h = reinterpret_cast<const __half2*>(&rv);
    #pragma unroll
    for (int k = 0; k < 4; ++k) {
        float2 f = __half22float2(h[k]);
        acc[2 * k]     = fmaf(w, f.x, acc[2 * k]);
        acc[2 * k + 1] = fmaf(w, f.y, acc[2 * k + 1]);
    }
}

__device__ __forceinline__ void agg_node(const float4* __restrict__ gt,
                                         const int2* __restrict__ pairs,
                                         int j, int end, int node, int q,
                                         float* __restrict__ acc) {
    for (; j + 4 <= end; j += 4) {
        int2 p0 = pairs[j], p1 = pairs[j + 1], p2 = pairs[j + 2], p3 = pairs[j + 3];
        float4 r0 = gt[(size_t)p0.x * 8 + q];
        float4 r1 = gt[(size_t)p1.x * 8 + q];
        float4 r2 = gt[(size_t)p2.x * 8 + q];
        float4 r3 = gt[(size_t)p3.x * 8 + q];
        accum8(acc, r0, __int_as_float(p0.y));
        accum8(acc, r1, __int_as_float(p1.y));
        accum8(acc, r2, __int_as_float(p2.y));
        accum8(acc, r3, __int_as_float(p3.y));
    }
    for (; j < end; ++j) {
        int2 p = pairs[j];
        float4 r = gt[(size_t)p.x * 8 + q];
        accum8(acc, r, __int_as_float(p.y));
    }
    float4 rs = gt[(size_t)node * 8 + q];   // self term, weight 1
    accum8(acc, rs, 1.0f);
}

// -------------------------------- fused layer: aggregate -> LDS -> GEMM64+ELU -> fp16
// Phase 1: 8 lanes/node, 32 nodes/block, agg rows (x dis) into fp32 LDS (stride 66).
// Phase 2: thread t -> node t&31, output slice t>>5; row hoisted to regs,
// WT reads wave-uniform (2 addrs/wave -> broadcast).
#define RS 66
__global__ __launch_bounds__(256) void layer_fused_kernel(const __half* __restrict__ gin,
                                                          const float* __restrict__ dis,
                                                          const int* __restrict__ offsets,
                                                          const int2* __restrict__ pairs,
                                                          const float* __restrict__ W,
                                                          const float* __restrict__ b,
                                                          __half* __restrict__ gout, int n) {
    __shared__ float rows[32 * RS];
    __shared__ float WT[64][64];     // WT[c][k] = W[k][c]
    __shared__ float bias_s[64];
    for (int idx = threadIdx.x; idx < 64 * 64; idx += 256) {
        int k = idx >> 6, c = idx & 63;
        WT[c][k] = W[idx];
    }
    if (threadIdx.x < 64) bias_s[threadIdx.x] = b[threadIdx.x];

    int tid = threadIdx.x;
    // ---- phase 1: aggregate ----
    {
        int ln = tid >> 3;                    // local node 0..31
        int q  = tid & 7;
        int gnode = blockIdx.x * 32 + ln;
        if (gnode < n) {
            const float4* gt = reinterpret_cast<const float4*>(gin);
            float acc[8] = {0.f, 0.f, 0.f, 0.f, 0.f, 0.f, 0.f, 0.f};
            agg_node(gt, pairs, offsets[gnode], offsets[gnode + 1], gnode, q, acc);
            float dn = dis[gnode];
            float* rp = &rows[ln * RS + q * 8];
            #pragma unroll
            for (int k2 = 0; k2 < 4; ++k2)
                *reinterpret_cast<float2*>(rp + 2 * k2) =
                    make_float2(dn * acc[2 * k2], dn * acc[2 * k2 + 1]);
        }
    }
    __syncthreads();
    // ---- phase 2: GEMM ----
    {
        int node2  = tid & 31;
        int slice  = tid >> 5;                // 0..7 -> outputs [8*slice, 8*slice+8)
        int gnode2 = blockIdx.x * 32 + node2;
        if (gnode2 < n) {
            float h[64];
            const float2* hp = reinterpret_cast<const float2*>(&rows[node2 * RS]);
            #pragma unroll
            for (int i = 0; i < 32; ++i) {
                float2 v = hp[i];
                h[2 * i] = v.x; h[2 * i + 1] = v.y;
            }
            float dn = dis[gnode2];
            int c0 = slice * 8;
            float r[8];
            #pragma unroll
            for (int cc = 0; cc < 8; ++cc) {
                const float4* wt = reinterpret_cast<const float4*>(&WT[c0 + cc][0]);
                float4 a = make_float4(0.f, 0.f, 0.f, 0.f);
                #pragma unroll
                for (int i = 0; i < 16; ++i) {
                    float4 w4 = wt[i];
                    a.x = fmaf(h[4 * i],     w4.x, a.x);
                    a.y = fmaf(h[4 * i + 1], w4.y, a.y);
                    a.z = fmaf(h[4 * i + 2], w4.z, a.z);
                    a.w = fmaf(h[4 * i + 3], w4.w, a.w);
                }
                float v = (a.x + a.y) + (a.z + a.w) + bias_s[c0 + cc];
                v = (v > 0.f) ? v : expm1f(v);          // ELU
                r[cc] = dn * v;                          // pre-scale for next layer
            }
            __half2 pk[4];
            pk[0] = __float22half2_rn(make_float2(r[0], r[1]));
            pk[1] = __float22half2_rn(make_float2(r[2], r[3]));
            pk[2] = __float22half2_rn(make_float2(r[4], r[5]));
            pk[3] = __float22half2_rn(make_float2(r[6], r[7]));
            *reinterpret_cast<float4*>(gout + (size_t)gnode2 * 64 + c0) =
                *reinterpret_cast<float4*>(pk);
        }
    }
}

// ---------------------------- standalone aggregate (layer 4), R8-proven form
__global__ __launch_bounds__(256) void aggregate_kernel(const __half* __restrict__ g,
                                                        const float* __restrict__ dis,
                                                        const int* __restrict__ offsets,
                                                        const int2* __restrict__ pairs,
                                                        __half* __restrict__ aggout, int n) {
    int node = blockIdx.x * 32 + (threadIdx.x >> 3);
    int q = threadIdx.x & 7;
    if (node >= n) return;
    const float4* gt = reinterpret_cast<const float4*>(g);
    float acc[8] = {0.f, 0.f, 0.f, 0.f, 0.f, 0.f, 0.f, 0.f};
    agg_node(gt, pairs, offsets[node], offsets[node + 1], node, q, acc);
    float dn = dis[node];
    __half2 o[4];
    o[0] = __float22half2_rn(make_float2(dn * acc[0], dn * acc[1]));
    o[1] = __float22half2_rn(make_float2(dn * acc[2], dn * acc[3]));
    o[2] = __float22half2_rn(make_float2(dn * acc[4], dn * acc[5]));
    o[3] = __float22half2_rn(make_float2(dn * acc[6], dn * acc[7]));
    reinterpret_cast<float4*>(aggout)[(size_t)node * 8 + q] = *reinterpret_cast<float4*>(o);
}

// ---- helper: load a 64-wide fp16 row into 64 fp32 registers
__device__ __forceinline__ void load_row64(const __half* __restrict__ in, int row,
                                           float* __restrict__ h) {
    const float4* inp = reinterpret_cast<const float4*>(in + (size_t)row * 64);
    #pragma unroll
    for (int i = 0; i < 8; ++i) {
        float4 raw = inp[i];
        const __half2* hp = reinterpret_cast<const __half2*>(&raw);
        #pragma unroll
        for (int k = 0; k < 4; ++k) {
            float2 f = __half22float2(hp[k]);
            h[i * 8 + 2 * k]     = f.x;
            h[i * 8 + 2 * k + 1] = f.y;
        }
    }
}

// ------------------------------- GEMM 64x40 + bias + fused row log_softmax -> d_out
__global__ __launch_bounds__(256) void gemm40_softmax_kernel(const __half* __restrict__ in,
                                                             const float* __restrict__ W,
                                                             const float* __restrict__ b,
                                                             float* __restrict__ out, int n) {
    __shared__ float WT[40][64];   // WT[c][k] = W[k][c]
    for (int idx = threadIdx.x; idx < 64 * 40; idx += 256) {
        int k = idx / 40, c = idx % 40;
        WT[c][k] = W[idx];
    }
    __syncthreads();

    int row = blockIdx.x * 256 + threadIdx.x;
    if (row >= n) return;

    float h[64];
    load_row64(in, row, h);

    float r[40];
    #pragma unroll 2
    for (int c = 0; c < 40; ++c) {
        const float4* wt = reinterpret_cast<const float4*>(&WT[c][0]);
        float4 a = make_float4(0.f, 0.f, 0.f, 0.f);
        #pragma unroll
        for (int i = 0; i < 16; ++i) {
            float4 w4 = wt[i];
            a.x = fmaf(h[4 * i],     w4.x, a.x);
            a.y = fmaf(h[4 * i + 1], w4.y, a.y);
            a.z = fmaf(h[4 * i + 2], w4.z, a.z);
            a.w = fmaf(h[4 * i + 3], w4.w, a.w);
        }
        r[c] = (a.x + a.y) + (a.z + a.w) + b[c];
    }

    float m = r[0];
    #pragma unroll
    for (int c = 1; c < 40; ++c) m = fmaxf(m, r[c]);
    float s = 0.f;
    #pragma unroll
    for (int c = 0; c < 40; ++c) s += expf(r[c] - m);
    float ls = logf(s) + m;

    float* outp = out + (size_t)row * 40;
    #pragma unroll
    for (int c4 = 0; c4 < 10; ++c4) {
        *reinterpret_cast<float4*>(outp + c4 * 4) =
            make_float4(r[c4 * 4] - ls, r[c4 * 4 + 1] - ls,
                        r[c4 * 4 + 2] - ls, r[c4 * 4 + 3] - ls);
    }
}

// ---------------------------------------------------------------- launch

static inline size_t align_up(size_t x, size_t a) { return (x + a - 1) & ~(a - 1); }

extern "C" void kernel_launch(void* const* d_in, const int* in_sizes, int n_in,
                              void* d_out, int out_size, void* d_ws, size_t ws_size,
                              hipStream_t stream) {
    const float* x  = (const float*)d_in[0];
    const int*   ei = (const int*)d_in[1];     // [2][E] flat: src then dst
    const float* ea = (const float*)d_in[2];
    const float* W1 = (const float*)d_in[3];
    const float* b1 = (const float*)d_in[4];
    const float* W2 = (const float*)d_in[5];
    const float* b2 = (const float*)d_in[6];
    const float* W3 = (const float*)d_in[7];
    const float* b3 = (const float*)d_in[8];
    const float* W4 = (const float*)d_in[9];
    const float* b4 = (const float*)d_in[10];

    const int N = in_sizes[0] / 64;
    const int E = in_sizes[1] / 2;

    const int* src = ei;
    const int* dst = ei + E;

    const int B = (N + 1023) / 1024;

    // workspace carve-up
    char* p = (char*)d_ws;
    int*    cnt     = (int*)p;    p += align_up((size_t)N * 4, 256);
    int*    offsets = (int*)p;    p += align_up(((size_t)N + 1) * 4, 256);
    int*    bsum    = (int*)p;    p += align_up(((size_t)B + 1) * 4, 256);
    float*  dis     = (float*)p;  p += align_up((size_t)N * 4, 256);
    int2*   pairs   = (int2*)p;   p += align_up(((size_t)E + 8) * 8, 256);
    __half* gA      = (__half*)p; p += align_up((size_t)N * 64 * 2, 256);
    __half* gB      = (__half*)p; p += align_up((size_t)N * 64 * 2, 256);
    int*    rank    = (int*)gB;   // aliases gB: dead before layer-1 writes gB
    (void)ws_size;

    const int nb_n   = (N + 255) / 256;
    const int nb_h   = (E + 2047) / 2048;       // hist ILP-8
    const int nb_sc  = (E + 1023) / 1024;       // scatter ILP-4
    const int nb_g16 = (N + 15) / 16;           // 16-lane-group kernels
    const int nb_f   = (N + 31) / 32;           // fused layer / aggregate blocks

    // --- graph preprocessing ---
    init_kernel<<<nb_n, 256, 0, stream>>>(cnt, N);
    hist_kernel<<<nb_h, 256, 0, stream>>>(dst, cnt, rank, E);
    scan_block_kernel<<<B, 256, 0, stream>>>(cnt, offsets, bsum, N);
    scan_bsum_kernel<<<1, 64, 0, stream>>>(bsum, B);
    scan_add_kernel<<<B, 256, 0, stream>>>(offsets, bsum, N, E);
    scatter_kernel<<<nb_sc, 256, 0, stream>>>(src, dst, ea, rank, offsets, pairs, E);
    rowsum_scale_kernel<<<nb_g16, 256, 0, stream>>>(offsets, pairs, x, dis, gA, N);

    // --- layers 1..3 fused (aggregate -> GEMM64+ELU -> fp16) ---
    layer_fused_kernel<<<nb_f, 256, 0, stream>>>(gA, dis, offsets, pairs, W1, b1, gB, N);
    layer_fused_kernel<<<nb_f, 256, 0, stream>>>(gB, dis, offsets, pairs, W2, b2, gA, N);
    layer_fused_kernel<<<nb_f, 256, 0, stream>>>(gA, dis, offsets, pairs, W3, b3, gB, N);

    // --- layer 4: aggregate then GEMM40 + log_softmax -> d_out ---
    aggregate_kernel<<<nb_f, 256, 0, stream>>>(gB, dis, offsets, pairs, gA, N);
    gemm40_softmax_kernel<<<nb_n, 256, 0, stream>>>(gA, W4, b4, (float*)d_out, N);
}

// Round 11
// 258.098 us; speedup vs baseline: 1.4344x; 1.2682x over previous
//
#include <hip/hip_runtime.h>
#include <hip/hip_fp16.h>
#include <cstdint>
#include <cmath>

// GCN, 4 layers. Structure: A(hW) = (Ah)W with norm folded into features:
//   g = dis (.) h  stored FP16,
//   A_norm h [d] = dis[d] * ( sum_e w_e * g[src_e] + g[d] )
// CSR built once per call (atomic hist w/ rank capture -> scan -> atomic-free
// scatter). Layers 1-3 fused: aggregate -> fp16 LDS rows -> GEMM64+ELU -> fp16.
// R10 post-mortem: fused kernel had 1.26e7 LDS bank conflicts (fp32 rows,
// stride 66, float2 reads), 25KB LDS (35% occupancy), 512 scalar FMA/thread.
// R11: rows handoff in fp16 half2 [32][33] (read bank = (node+i)%32, conflict
// free), WT staged fp16, inner product via v_dot2_f32_f16 (fp32 accumulator,
// halves VALU), LDS 25->12.7KB. gemm40_softmax gets the same treatment.
// hist untouched (device returning-atomic wall ~23 G/s, proven R6/R8/R9).

// ---- fdot2: 2x f16 MAC with fp32 accumulator (guarded builtin)
__device__ __forceinline__ float fdot2f(__half2 a, __half2 b, float c) {
#if defined(__has_builtin)
#if __has_builtin(__builtin_amdgcn_fdot2)
    typedef _Float16 h2v __attribute__((ext_vector_type(2)));
    return __builtin_amdgcn_fdot2(__builtin_bit_cast(h2v, a),
                                  __builtin_bit_cast(h2v, b), c, false);
#else
    float2 fa = __half22float2(a), fb = __half22float2(b);
    return fmaf(fa.x, fb.x, fmaf(fa.y, fb.y, c));
#endif
#else
    float2 fa = __half22float2(a), fb = __half22float2(b);
    return fmaf(fa.x, fb.x, fmaf(fa.y, fb.y, c));
#endif
}

// ---------------------------------------------------------------- setup

__global__ __launch_bounds__(256) void init_kernel(int* __restrict__ cnt, int n) {
    int i = blockIdx.x * 256 + threadIdx.x;
    if (i < n) cnt[i] = 0;
}

// count edges per destination; atomic return = rank of edge within its row.
__global__ __launch_bounds__(256) void hist_kernel(const int* __restrict__ dst,
                                                   int* __restrict__ cnt,
                                                   int* __restrict__ rank, int E) {
    int t = blockIdx.x * 2048 + threadIdx.x;
    if (t + 1792 < E) {
        int d[8];
        #pragma unroll
        for (int u = 0; u < 8; ++u) d[u] = dst[t + u * 256];
        int r[8];
        #pragma unroll
        for (int u = 0; u < 8; ++u) r[u] = atomicAdd(&cnt[d[u]], 1);
        #pragma unroll
        for (int u = 0; u < 8; ++u) rank[t + u * 256] = r[u];
    } else {
        #pragma unroll
        for (int u = 0; u < 8; ++u) {
            int e = t + u * 256;
            if (e < E) rank[e] = atomicAdd(&cnt[dst[e]], 1);
        }
    }
}

// ------------------------------------------------- device-wide scan (3 kernels)

__global__ __launch_bounds__(256) void scan_block_kernel(const int* __restrict__ cnt,
                                                         int* __restrict__ offsets,
                                                         int* __restrict__ bsum, int n) {
    __shared__ int wtot[4];
    int t = threadIdx.x;
    int i = blockIdx.x * 1024 + t * 4;
    int4 v = make_int4(0, 0, 0, 0);
    if (i + 3 < n) v = *reinterpret_cast<const int4*>(cnt + i);
    else {
        if (i     < n) v.x = cnt[i];
        if (i + 1 < n) v.y = cnt[i + 1];
        if (i + 2 < n) v.z = cnt[i + 2];
        if (i + 3 < n) v.w = cnt[i + 3];
    }
    int tsum = v.x + v.y + v.z + v.w;
    int lane = t & 63, wid = t >> 6;
    int x = tsum;
    #pragma unroll
    for (int off = 1; off < 64; off <<= 1) {
        int tt = __shfl_up(x, off);
        if (lane >= off) x += tt;
    }
    if (lane == 63) wtot[wid] = x;
    __syncthreads();
    int wbase = 0;
    #pragma unroll
    for (int wv = 0; wv < 4; ++wv) if (wv < wid) wbase += wtot[wv];
    int e0 = wbase + x - tsum;
    int4 o;
    o.x = e0; o.y = e0 + v.x; o.z = o.y + v.y; o.w = o.z + v.z;
    if (i + 3 < n) *reinterpret_cast<int4*>(offsets + i) = o;
    else {
        if (i     < n) offsets[i]     = o.x;
        if (i + 1 < n) offsets[i + 1] = o.y;
        if (i + 2 < n) offsets[i + 2] = o.z;
        if (i + 3 < n) offsets[i + 3] = o.w;
    }
    if (t == 255) bsum[blockIdx.x] = wbase + x;
}

__global__ __launch_bounds__(64) void scan_bsum_kernel(int* __restrict__ bsum, int B) {
    int lane = threadIdx.x;
    int run = 0;
    for (int base = 0; base < B; base += 64) {
        int i = base + lane;
        int v = (i < B) ? bsum[i] : 0;
        int x = v;
        #pragma unroll
        for (int off = 1; off < 64; off <<= 1) {
            int t = __shfl_up(x, off);
            if (lane >= off) x += t;
        }
        if (i < B) bsum[i] = run + x - v;
        run += __shfl(x, 63);
    }
}

__global__ __launch_bounds__(256) void scan_add_kernel(int* __restrict__ offsets,
                                                       const int* __restrict__ bsum,
                                                       int n, int E) {
    int base = bsum[blockIdx.x];
    int i = blockIdx.x * 1024 + threadIdx.x * 4;
    if (i + 3 < n) {
        int4 o = *reinterpret_cast<int4*>(offsets + i);
        o.x += base; o.y += base; o.z += base; o.w += base;
        *reinterpret_cast<int4*>(offsets + i) = o;
    } else {
        for (int k = 0; k < 4; ++k) if (i + k < n) offsets[i + k] += base;
    }
    if (blockIdx.x == 0 && threadIdx.x == 0) offsets[n] = E;
}

// scatter, atomic-free: pairs[offsets[dst]+rank] = (src, raw weight). ILP-4.
__global__ __launch_bounds__(256) void scatter_kernel(const int* __restrict__ src,
                                                      const int* __restrict__ dst,
                                                      const float* __restrict__ w,
                                                      const int* __restrict__ rank,
                                                      const int* __restrict__ offsets,
                                                      int2* __restrict__ pairs, int E) {
    int t = blockIdx.x * 1024 + threadIdx.x;
    if (t + 768 < E) {
        int d[4], s[4], r[4]; float wv[4];
        #pragma unroll
        for (int u = 0; u < 4; ++u) {
            int e = t + u * 256;
            d[u] = dst[e]; s[u] = src[e]; wv[u] = w[e]; r[u] = rank[e];
        }
        int o[4];
        #pragma unroll
        for (int u = 0; u < 4; ++u) o[u] = offsets[d[u]];
        #pragma unroll
        for (int u = 0; u < 4; ++u)
            pairs[o[u] + r[u]] = make_int2(s[u], __float_as_int(wv[u]));
    } else {
        #pragma unroll
        for (int u = 0; u < 4; ++u) {
            int e = t + u * 256;
            if (e < E)
                pairs[offsets[dst[e]] + rank[e]] = make_int2(src[e], __float_as_int(w[e]));
        }
    }
}

// fused: deg row-sum -> dis -> g0 = fp16(dis (.) x). 16 lanes per node.
__global__ __launch_bounds__(256) void rowsum_scale_kernel(const int* __restrict__ offsets,
                                                           const int2* __restrict__ pairs,
                                                           const float* __restrict__ x,
                                                           float* __restrict__ dis,
                                                           __half* __restrict__ g, int n) {
    int node = blockIdx.x * 16 + (threadIdx.x >> 4);
    int q = threadIdx.x & 15;
    if (node >= n) return;
    int j0 = offsets[node], end = offsets[node + 1];
    float s = 0.f;
    for (int j = j0 + q; j < end; j += 16) s += __int_as_float(pairs[j].y);
    #pragma unroll
    for (int off = 8; off; off >>= 1) s += __shfl_xor(s, off);
    float dn = rsqrtf(1.0f + s);
    if (q == 0) dis[node] = dn;
    float4 v = reinterpret_cast<const float4*>(x)[(size_t)node * 16 + q];
    __half2 pk[2];
    pk[0] = __float22half2_rn(make_float2(dn * v.x, dn * v.y));
    pk[1] = __float22half2_rn(make_float2(dn * v.z, dn * v.w));
    reinterpret_cast<float2*>(g + (size_t)node * 64)[q] = *reinterpret_cast<float2*>(pk);
}

// ---------------------------------------------------------------- aggregation core
// 8-lane group per node; lane q owns half8 #q (features 8q..8q+7). fp32 accum.
__device__ __forceinline__ void accum8(float* acc, float4 rv, float w) {
    const __half2* h = reinterpret_cast<const __half2*>(&rv);
    #pragma unroll
    for (int k = 0; k < 4; ++k) {
        float2 f = __half22float2(h[k]);
        acc[2 * k]     = fmaf(w, f.x, acc[2 * k]);
        acc[2 * k + 1] = fmaf(w, f.y, acc[2 * k + 1]);
    }
}

__device__ __forceinline__ void agg_node(const float4* __restrict__ gt,
                                         const int2* __restrict__ pairs,
                                         int j, int end, int node, int q,
                                         float* __restrict__ acc) {
    for (; j + 4 <= end; j += 4) {
        int2 p0 = pairs[j], p1 = pairs[j + 1], p2 = pairs[j + 2], p3 = pairs[j + 3];
        float4 r0 = gt[(size_t)p0.x * 8 + q];
        float4 r1 = gt[(size_t)p1.x * 8 + q];
        float4 r2 = gt[(size_t)p2.x * 8 + q];
        float4 r3 = gt[(size_t)p3.x * 8 + q];
        accum8(acc, r0, __int_as_float(p0.y));
        accum8(acc, r1, __int_as_float(p1.y));
        accum8(acc, r2, __int_as_float(p2.y));
        accum8(acc, r3, __int_as_float(p3.y));
    }
    for (; j < end; ++j) {
        int2 p = pairs[j];
        float4 r = gt[(size_t)p.x * 8 + q];
        accum8(acc, r, __int_as_float(p.y));
    }
    float4 rs = gt[(size_t)node * 8 + q];   // self term, weight 1
    accum8(acc, rs, 1.0f);
}

// -------------------------------- fused layer: aggregate -> LDS fp16 -> GEMM64+ELU -> fp16
// Phase 1: 8 lanes/node, 32 nodes/block, agg rows (x dis) into half2 LDS [32][33]
//          (read bank = (node+i)%32 -> conflict-free phase-2 reads).
// Phase 2: thread t -> node t&31, output slice t>>5 (8 outputs); row hoisted to
//          32 half2 regs, WT fp16 half2 (wave-uniform reads), fdot2 fp32 accum.
__global__ __launch_bounds__(256) void layer_fused_kernel(const __half* __restrict__ gin,
                                                          const float* __restrict__ dis,
                                                          const int* __restrict__ offsets,
                                                          const int2* __restrict__ pairs,
                                                          const float* __restrict__ W,
                                                          const float* __restrict__ b,
                                                          __half* __restrict__ gout, int n) {
    __shared__ __half2 rows[32][33];
    __shared__ __half2 WT[64][32];   // WT[c][k2] = (W[2k2][c], W[2k2+1][c]) fp16
    __shared__ float bias_s[64];
    for (int idx = threadIdx.x; idx < 64 * 32; idx += 256) {
        int k2 = idx >> 6, c = idx & 63;
        WT[c][k2] = __float22half2_rn(make_float2(W[(2 * k2) * 64 + c],
                                                  W[(2 * k2 + 1) * 64 + c]));
    }
    if (threadIdx.x < 64) bias_s[threadIdx.x] = b[threadIdx.x];

    int tid = threadIdx.x;
    // ---- phase 1: aggregate ----
    {
        int ln = tid >> 3;                    // local node 0..31
        int q  = tid & 7;
        int gnode = blockIdx.x * 32 + ln;
        if (gnode < n) {
            const float4* gt = reinterpret_cast<const float4*>(gin);
            float acc[8] = {0.f, 0.f, 0.f, 0.f, 0.f, 0.f, 0.f, 0.f};
            agg_node(gt, pairs, offsets[gnode], offsets[gnode + 1], gnode, q, acc);
            float dn = dis[gnode];
            #pragma unroll
            for (int k2 = 0; k2 < 4; ++k2)
                rows[ln][q * 4 + k2] =
                    __float22half2_rn(make_float2(dn * acc[2 * k2], dn * acc[2 * k2 + 1]));
        }
    }
    __syncthreads();
    // ---- phase 2: GEMM (fdot2) ----
    {
        int node2  = tid & 31;
        int slice  = tid >> 5;                // 0..7 -> outputs [8*slice, 8*slice+8)
        int gnode2 = blockIdx.x * 32 + node2;
        if (gnode2 < n) {
            __half2 h2[32];
            #pragma unroll
            for (int i = 0; i < 32; ++i) h2[i] = rows[node2][i];

            float dn = dis[gnode2];
            int c0 = slice * 8;
            float r[8];
            #pragma unroll
            for (int cc = 0; cc < 8; ++cc) {
                const __half2* wt = &WT[c0 + cc][0];
                float a0 = 0.f, a1 = 0.f, a2 = 0.f, a3 = 0.f;
                #pragma unroll
                for (int i = 0; i < 8; ++i) {
                    a0 = fdot2f(h2[4 * i],     wt[4 * i],     a0);
                    a1 = fdot2f(h2[4 * i + 1], wt[4 * i + 1], a1);
                    a2 = fdot2f(h2[4 * i + 2], wt[4 * i + 2], a2);
                    a3 = fdot2f(h2[4 * i + 3], wt[4 * i + 3], a3);
                }
                float v = (a0 + a1) + (a2 + a3) + bias_s[c0 + cc];
                v = (v > 0.f) ? v : expm1f(v);          // ELU
                r[cc] = dn * v;                          // pre-scale for next layer
            }
            __half2 pk[4];
            pk[0] = __float22half2_rn(make_float2(r[0], r[1]));
            pk[1] = __float22half2_rn(make_float2(r[2], r[3]));
            pk[2] = __float22half2_rn(make_float2(r[4], r[5]));
            pk[3] = __float22half2_rn(make_float2(r[6], r[7]));
            *reinterpret_cast<float4*>(gout + (size_t)gnode2 * 64 + c0) =
                *reinterpret_cast<float4*>(pk);
        }
    }
}

// ---------------------------- standalone aggregate (layer 4), R8-proven form
__global__ __launch_bounds__(256) void aggregate_kernel(const __half* __restrict__ g,
                                                        const float* __restrict__ dis,
                                                        const int* __restrict__ offsets,
                                                        const int2* __restrict__ pairs,
                                                        __half* __restrict__ aggout, int n) {
    int node = blockIdx.x * 32 + (threadIdx.x >> 3);
    int q = threadIdx.x & 7;
    if (node >= n) return;
    const float4* gt = reinterpret_cast<const float4*>(g);
    float acc[8] = {0.f, 0.f, 0.f, 0.f, 0.f, 0.f, 0.f, 0.f};
    agg_node(gt, pairs, offsets[node], offsets[node + 1], node, q, acc);
    float dn = dis[node];
    __half2 o[4];
    o[0] = __float22half2_rn(make_float2(dn * acc[0], dn * acc[1]));
    o[1] = __float22half2_rn(make_float2(dn * acc[2], dn * acc[3]));
    o[2] = __float22half2_rn(make_float2(dn * acc[4], dn * acc[5]));
    o[3] = __float22half2_rn(make_float2(dn * acc[6], dn * acc[7]));
    reinterpret_cast<float4*>(aggout)[(size_t)node * 8 + q] = *reinterpret_cast<float4*>(o);
}

// ------------------------------- GEMM 64x40 (fdot2) + bias + row log_softmax -> d_out
__global__ __launch_bounds__(256) void gemm40_softmax_kernel(const __half* __restrict__ in,
                                                             const float* __restrict__ W,
                                                             const float* __restrict__ b,
                                                             float* __restrict__ out, int n) {
    __shared__ __half2 WT[40][32];   // WT[c][k2] = (W[2k2][c], W[2k2+1][c]) fp16
    for (int idx = threadIdx.x; idx < 40 * 32; idx += 256) {
        int c = idx % 40, k2 = idx / 40;
        WT[c][k2] = __float22half2_rn(make_float2(W[(2 * k2) * 40 + c],
                                                  W[(2 * k2 + 1) * 40 + c]));
    }
    __syncthreads();

    int row = blockIdx.x * 256 + threadIdx.x;
    if (row >= n) return;

    // load fp16 row directly as 32 half2 (no conversion)
    __half2 h2[32];
    const float4* inp = reinterpret_cast<const float4*>(in + (size_t)row * 64);
    #pragma unroll
    for (int i = 0; i < 8; ++i) {
        float4 raw = inp[i];
        const __half2* hp = reinterpret_cast<const __half2*>(&raw);
        h2[4 * i] = hp[0]; h2[4 * i + 1] = hp[1];
        h2[4 * i + 2] = hp[2]; h2[4 * i + 3] = hp[3];
    }

    float r[40];
    #pragma unroll 2
    for (int c = 0; c < 40; ++c) {
        const __half2* wt = &WT[c][0];
        float a0 = 0.f, a1 = 0.f, a2 = 0.f, a3 = 0.f;
        #pragma unroll
        for (int i = 0; i < 8; ++i) {
            a0 = fdot2f(h2[4 * i],     wt[4 * i],     a0);
            a1 = fdot2f(h2[4 * i + 1], wt[4 * i + 1], a1);
            a2 = fdot2f(h2[4 * i + 2], wt[4 * i + 2], a2);
            a3 = fdot2f(h2[4 * i + 3], wt[4 * i + 3], a3);
        }
        r[c] = (a0 + a1) + (a2 + a3) + b[c];
    }

    float m = r[0];
    #pragma unroll
    for (int c = 1; c < 40; ++c) m = fmaxf(m, r[c]);
    float s = 0.f;
    #pragma unroll
    for (int c = 0; c < 40; ++c) s += expf(r[c] - m);
    float ls = logf(s) + m;

    float* outp = out + (size_t)row * 40;
    #pragma unroll
    for (int c4 = 0; c4 < 10; ++c4) {
        *reinterpret_cast<float4*>(outp + c4 * 4) =
            make_float4(r[c4 * 4] - ls, r[c4 * 4 + 1] - ls,
                        r[c4 * 4 + 2] - ls, r[c4 * 4 + 3] - ls);
    }
}

// ---------------------------------------------------------------- launch

static inline size_t align_up(size_t x, size_t a) { return (x + a - 1) & ~(a - 1); }

extern "C" void kernel_launch(void* const* d_in, const int* in_sizes, int n_in,
                              void* d_out, int out_size, void* d_ws, size_t ws_size,
                              hipStream_t stream) {
    const float* x  = (const float*)d_in[0];
    const int*   ei = (const int*)d_in[1];     // [2][E] flat: src then dst
    const float* ea = (const float*)d_in[2];
    const float* W1 = (const float*)d_in[3];
    const float* b1 = (const float*)d_in[4];
    const float* W2 = (const float*)d_in[5];
    const float* b2 = (const float*)d_in[6];
    const float* W3 = (const float*)d_in[7];
    const float* b3 = (const float*)d_in[8];
    const float* W4 = (const float*)d_in[9];
    const float* b4 = (const float*)d_in[10];

    const int N = in_sizes[0] / 64;
    const int E = in_sizes[1] / 2;

    const int* src = ei;
    const int* dst = ei + E;

    const int B = (N + 1023) / 1024;

    // workspace carve-up
    char* p = (char*)d_ws;
    int*    cnt     = (int*)p;    p += align_up((size_t)N * 4, 256);
    int*    offsets = (int*)p;    p += align_up(((size_t)N + 1) * 4, 256);
    int*    bsum    = (int*)p;    p += align_up(((size_t)B + 1) * 4, 256);
    float*  dis     = (float*)p;  p += align_up((size_t)N * 4, 256);
    int2*   pairs   = (int2*)p;   p += align_up(((size_t)E + 8) * 8, 256);
    __half* gA      = (__half*)p; p += align_up((size_t)N * 64 * 2, 256);
    __half* gB      = (__half*)p; p += align_up((size_t)N * 64 * 2, 256);
    int*    rank    = (int*)gB;   // aliases gB: dead before layer-1 writes gB
    (void)ws_size;

    const int nb_n   = (N + 255) / 256;
    const int nb_h   = (E + 2047) / 2048;       // hist ILP-8
    const int nb_sc  = (E + 1023) / 1024;       // scatter ILP-4
    const int nb_g16 = (N + 15) / 16;           // 16-lane-group kernels
    const int nb_f   = (N + 31) / 32;           // fused layer / aggregate blocks

    // --- graph preprocessing ---
    init_kernel<<<nb_n, 256, 0, stream>>>(cnt, N);
    hist_kernel<<<nb_h, 256, 0, stream>>>(dst, cnt, rank, E);
    scan_block_kernel<<<B, 256, 0, stream>>>(cnt, offsets, bsum, N);
    scan_bsum_kernel<<<1, 64, 0, stream>>>(bsum, B);
    scan_add_kernel<<<B, 256, 0, stream>>>(offsets, bsum, N, E);
    scatter_kernel<<<nb_sc, 256, 0, stream>>>(src, dst, ea, rank, offsets, pairs, E);
    rowsum_scale_kernel<<<nb_g16, 256, 0, stream>>>(offsets, pairs, x, dis, gA, N);

    // --- layers 1..3 fused (aggregate -> GEMM64+ELU -> fp16) ---
    layer_fused_kernel<<<nb_f, 256, 0, stream>>>(gA, dis, offsets, pairs, W1, b1, gB, N);
    layer_fused_kernel<<<nb_f, 256, 0, stream>>>(gB, dis, offsets, pairs, W2, b2, gA, N);
    layer_fused_kernel<<<nb_f, 256, 0, stream>>>(gA, dis, offsets, pairs, W3, b3, gB, N);

    // --- layer 4: aggregate then GEMM40 + log_softmax -> d_out ---
    aggregate_kernel<<<nb_f, 256, 0, stream>>>(gB, dis, offsets, pairs, gA, N);
    gemm40_softmax_kernel<<<nb_n, 256, 0, stream>>>(gA, W4, b4, (float*)d_out, N);
}

// Round 12
// 222.819 us; speedup vs baseline: 1.6615x; 1.1583x over previous
//
#include <hip/hip_runtime.h>
#include <hip/hip_fp16.h>
#include <cstdint>
#include <cmath>

// GCN, 4 layers. Structure: A(hW) = (Ah)W with norm folded into features:
//   g = dis (.) h  stored FP16,
//   A_norm h [d] = dis[d] * ( sum_e w_e * g[src_e] + g[d] )
// Layers 1-3 fused: aggregate -> fp16 LDS rows [32][33] -> fdot2 GEMM64+ELU -> fp16
// (R11-proven). Layer 4: standalone aggregate + fdot2 GEMM40 + log_softmax.
//
// R12: CSR build rebuilt as a two-level LDS counting sort. The old
// hist(53us)+scan(5)+scatter(14) was pinned by the device returning-atomic
// wall (~23 G/s, invariant across ILP 1..8 / occupancy 18..63%, R6/R8/R9).
// New path: per-block LDS bucket histogram (196 buckets of 512 nodes) ->
// ONE global atomic per (block,bucket) = 57K atomics (21x fewer) ->
// bucket-contiguous temp via LDS cursors -> per-bucket block builds the
// final CSR entirely with LDS atomics. Within-row edge order is atomic-
// arrival-dependent (same class as old rank capture; fp32-sum noise << thr).

#define NPB_SHIFT 9
#define NPB 512              // nodes per bucket
#define CHUNK 4096           // edges per block in count/scatter passes

// ---- fdot2: 2x f16 MAC with fp32 accumulator (guarded builtin)
__device__ __forceinline__ float fdot2f(__half2 a, __half2 b, float c) {
#if defined(__has_builtin)
#if __has_builtin(__builtin_amdgcn_fdot2)
    typedef _Float16 h2v __attribute__((ext_vector_type(2)));
    return __builtin_amdgcn_fdot2(__builtin_bit_cast(h2v, a),
                                  __builtin_bit_cast(h2v, b), c, false);
#else
    float2 fa = __half22float2(a), fb = __half22float2(b);
    return fmaf(fa.x, fb.x, fmaf(fa.y, fb.y, c));
#endif
#else
    float2 fa = __half22float2(a), fb = __half22float2(b);
    return fmaf(fa.x, fb.x, fmaf(fa.y, fb.y, c));
#endif
}

// ------------------------------------------- CSR build: two-level counting sort

__global__ __launch_bounds__(256) void bucket_init_kernel(int* __restrict__ bucket_cnt,
                                                          int nbuck) {
    if ((int)threadIdx.x < nbuck) bucket_cnt[threadIdx.x] = 0;
}

// A: per-block LDS histogram of dst>>9; one returning global atomic per
// (block,bucket) captures this block's base within the bucket.
__global__ __launch_bounds__(256) void bucket_count_kernel(const int* __restrict__ dst,
                                                           int* __restrict__ bucket_cnt,
                                                           int* __restrict__ blockbase,
                                                           int nbuck, int E) {
    __shared__ int hist[256];
    int tid = threadIdx.x;
    hist[tid] = 0;
    __syncthreads();
    int base = blockIdx.x * CHUNK;
    #pragma unroll
    for (int u = 0; u < CHUNK / 256; ++u) {
        int e = base + u * 256 + tid;
        if (e < E) atomicAdd(&hist[dst[e] >> NPB_SHIFT], 1);
    }
    __syncthreads();
    if (tid < nbuck)
        blockbase[blockIdx.x * nbuck + tid] = atomicAdd(&bucket_cnt[tid], hist[tid]);
}

// B: exclusive scan of bucket counts -> bucket bases (single wave)
__global__ __launch_bounds__(64) void bucket_scan_kernel(const int* __restrict__ bucket_cnt,
                                                         int* __restrict__ bucket_base,
                                                         int nbuck, int E) {
    int lane = threadIdx.x;
    int run = 0;
    for (int b0 = 0; b0 < nbuck; b0 += 64) {
        int i = b0 + lane;
        int v = (i < nbuck) ? bucket_cnt[i] : 0;
        int x = v;
        #pragma unroll
        for (int off = 1; off < 64; off <<= 1) {
            int t = __shfl_up(x, off);
            if (lane >= off) x += t;
        }
        if (i < nbuck) bucket_base[i] = run + x - v;
        run += __shfl(x, 63);
    }
    if (lane == 0) bucket_base[nbuck] = E;
}

// C: scatter edges into bucket-contiguous temp via LDS cursors.
// temp record: (src | dstlocal<<17, w_bits)  [src<2^17, dstlocal<2^9]
__global__ __launch_bounds__(256) void bucket_scatter_kernel(const int* __restrict__ src,
                                                             const int* __restrict__ dst,
                                                             const float* __restrict__ w,
                                                             const int* __restrict__ bucket_base,
                                                             const int* __restrict__ blockbase,
                                                             int2* __restrict__ temp,
                                                             int nbuck, int E) {
    __shared__ int cursor[256];
    int tid = threadIdx.x;
    if (tid < nbuck)
        cursor[tid] = bucket_base[tid] + blockbase[blockIdx.x * nbuck + tid];
    __syncthreads();
    int base = blockIdx.x * CHUNK;
    #pragma unroll
    for (int u = 0; u < CHUNK / 256; ++u) {
        int e = base + u * 256 + tid;
        if (e < E) {
            int d = dst[e];
            int pos = atomicAdd(&cursor[d >> NPB_SHIFT], 1);
            temp[pos] = make_int2(src[e] | ((d & (NPB - 1)) << 17),
                                  __float_as_int(w[e]));
        }
    }
}

// D: one block per bucket. LDS count(512) -> LDS scan -> global offsets ->
// place edges into final pairs via LDS cursors. No global atomics.
__global__ __launch_bounds__(256) void bucket_csr_kernel(const int2* __restrict__ temp,
                                                         const int* __restrict__ bucket_base,
                                                         int* __restrict__ offsets,
                                                         int2* __restrict__ pairs,
                                                         int n, int E) {
    __shared__ int cnt[NPB];
    __shared__ int wtot[4];
    int tid = threadIdx.x;
    int bk = blockIdx.x;
    int base = bucket_base[bk], end = bucket_base[bk + 1];
    cnt[tid] = 0; cnt[tid + 256] = 0;
    __syncthreads();
    for (int j = base + tid; j < end; j += 256)
        atomicAdd(&cnt[temp[j].x >> 17], 1);
    __syncthreads();
    // exclusive scan of cnt[512]; thread t owns elements 2t, 2t+1
    int a0 = cnt[2 * tid], a1 = cnt[2 * tid + 1];
    int s = a0 + a1;
    int lane = tid & 63, wid = tid >> 6;
    int x = s;
    #pragma unroll
    for (int off = 1; off < 64; off <<= 1) {
        int t2 = __shfl_up(x, off);
        if (lane >= off) x += t2;
    }
    if (lane == 63) wtot[wid] = x;
    __syncthreads();
    int wbase = 0;
    #pragma unroll
    for (int wv = 0; wv < 4; ++wv) if (wv < wid) wbase += wtot[wv];
    int e0 = wbase + x - s;                  // exclusive prefix of element 2t
    int abs0 = base + e0, abs1 = base + e0 + a0;
    int node0 = bk * NPB + 2 * tid;
    if (node0 < n)     offsets[node0]     = abs0;
    if (node0 + 1 < n) offsets[node0 + 1] = abs1;
    __syncthreads();                         // scan reads done; reuse cnt as cursors
    cnt[2 * tid] = abs0; cnt[2 * tid + 1] = abs1;
    __syncthreads();
    for (int j = base + tid; j < end; j += 256) {
        int2 t2 = temp[j];
        int pos = atomicAdd(&cnt[t2.x >> 17], 1);
        pairs[pos] = make_int2(t2.x & 0x1FFFF, t2.y);
    }
    if (bk == 0 && tid == 0) offsets[n] = E;
}

// fused: deg row-sum -> dis -> g0 = fp16(dis (.) x). 16 lanes per node.
__global__ __launch_bounds__(256) void rowsum_scale_kernel(const int* __restrict__ offsets,
                                                           const int2* __restrict__ pairs,
                                                           const float* __restrict__ x,
                                                           float* __restrict__ dis,
                                                           __half* __restrict__ g, int n) {
    int node = blockIdx.x * 16 + (threadIdx.x >> 4);
    int q = threadIdx.x & 15;
    if (node >= n) return;
    int j0 = offsets[node], end = offsets[node + 1];
    float s = 0.f;
    for (int j = j0 + q; j < end; j += 16) s += __int_as_float(pairs[j].y);
    #pragma unroll
    for (int off = 8; off; off >>= 1) s += __shfl_xor(s, off);
    float dn = rsqrtf(1.0f + s);
    if (q == 0) dis[node] = dn;
    float4 v = reinterpret_cast<const float4*>(x)[(size_t)node * 16 + q];
    __half2 pk[2];
    pk[0] = __float22half2_rn(make_float2(dn * v.x, dn * v.y));
    pk[1] = __float22half2_rn(make_float2(dn * v.z, dn * v.w));
    reinterpret_cast<float2*>(g + (size_t)node * 64)[q] = *reinterpret_cast<float2*>(pk);
}

// ---------------------------------------------------------------- aggregation core
// 8-lane group per node; lane q owns half8 #q (features 8q..8q+7). fp32 accum.
__device__ __forceinline__ void accum8(float* acc, float4 rv, float w) {
    const __half2* h = reinterpret_cast<const __half2*>(&rv);
    #pragma unroll
    for (int k = 0; k < 4; ++k) {
        float2 f = __half22float2(h[k]);
        acc[2 * k]     = fmaf(w, f.x, acc[2 * k]);
        acc[2 * k + 1] = fmaf(w, f.y, acc[2 * k + 1]);
    }
}

__device__ __forceinline__ void agg_node(const float4* __restrict__ gt,
                                         const int2* __restrict__ pairs,
                                         int j, int end, int node, int q,
                                         float* __restrict__ acc) {
    for (; j + 4 <= end; j += 4) {
        int2 p0 = pairs[j], p1 = pairs[j + 1], p2 = pairs[j + 2], p3 = pairs[j + 3];
        float4 r0 = gt[(size_t)p0.x * 8 + q];
        float4 r1 = gt[(size_t)p1.x * 8 + q];
        float4 r2 = gt[(size_t)p2.x * 8 + q];
        float4 r3 = gt[(size_t)p3.x * 8 + q];
        accum8(acc, r0, __int_as_float(p0.y));
        accum8(acc, r1, __int_as_float(p1.y));
        accum8(acc, r2, __int_as_float(p2.y));
        accum8(acc, r3, __int_as_float(p3.y));
    }
    for (; j < end; ++j) {
        int2 p = pairs[j];
        float4 r = gt[(size_t)p.x * 8 + q];
        accum8(acc, r, __int_as_float(p.y));
    }
    float4 rs = gt[(size_t)node * 8 + q];   // self term, weight 1
    accum8(acc, rs, 1.0f);
}

// -------------------------------- fused layer: aggregate -> LDS fp16 -> GEMM64+ELU -> fp16
__global__ __launch_bounds__(256) void layer_fused_kernel(const __half* __restrict__ gin,
                                                          const float* __restrict__ dis,
                                                          const int* __restrict__ offsets,
                                                          const int2* __restrict__ pairs,
                                                          const float* __restrict__ W,
                                                          const float* __restrict__ b,
                                                          __half* __restrict__ gout, int n) {
    __shared__ __half2 rows[32][33];
    __shared__ __half2 WT[64][32];   // WT[c][k2] = (W[2k2][c], W[2k2+1][c]) fp16
    __shared__ float bias_s[64];
    for (int idx = threadIdx.x; idx < 64 * 32; idx += 256) {
        int k2 = idx >> 6, c = idx & 63;
        WT[c][k2] = __float22half2_rn(make_float2(W[(2 * k2) * 64 + c],
                                                  W[(2 * k2 + 1) * 64 + c]));
    }
    if (threadIdx.x < 64) bias_s[threadIdx.x] = b[threadIdx.x];

    int tid = threadIdx.x;
    // ---- phase 1: aggregate ----
    {
        int ln = tid >> 3;
        int q  = tid & 7;
        int gnode = blockIdx.x * 32 + ln;
        if (gnode < n) {
            const float4* gt = reinterpret_cast<const float4*>(gin);
            float acc[8] = {0.f, 0.f, 0.f, 0.f, 0.f, 0.f, 0.f, 0.f};
            agg_node(gt, pairs, offsets[gnode], offsets[gnode + 1], gnode, q, acc);
            float dn = dis[gnode];
            #pragma unroll
            for (int k2 = 0; k2 < 4; ++k2)
                rows[ln][q * 4 + k2] =
                    __float22half2_rn(make_float2(dn * acc[2 * k2], dn * acc[2 * k2 + 1]));
        }
    }
    __syncthreads();
    // ---- phase 2: GEMM (fdot2) ----
    {
        int node2  = tid & 31;
        int slice  = tid >> 5;
        int gnode2 = blockIdx.x * 32 + node2;
        if (gnode2 < n) {
            __half2 h2[32];
            #pragma unroll
            for (int i = 0; i < 32; ++i) h2[i] = rows[node2][i];

            float dn = dis[gnode2];
            int c0 = slice * 8;
            float r[8];
            #pragma unroll
            for (int cc = 0; cc < 8; ++cc) {
                const __half2* wt = &WT[c0 + cc][0];
                float a0 = 0.f, a1 = 0.f, a2 = 0.f, a3 = 0.f;
                #pragma unroll
                for (int i = 0; i < 8; ++i) {
                    a0 = fdot2f(h2[4 * i],     wt[4 * i],     a0);
                    a1 = fdot2f(h2[4 * i + 1], wt[4 * i + 1], a1);
                    a2 = fdot2f(h2[4 * i + 2], wt[4 * i + 2], a2);
                    a3 = fdot2f(h2[4 * i + 3], wt[4 * i + 3], a3);
                }
                float v = (a0 + a1) + (a2 + a3) + bias_s[c0 + cc];
                v = (v > 0.f) ? v : expm1f(v);          // ELU
                r[cc] = dn * v;                          // pre-scale for next layer
            }
            __half2 pk[4];
            pk[0] = __float22half2_rn(make_float2(r[0], r[1]));
            pk[1] = __float22half2_rn(make_float2(r[2], r[3]));
            pk[2] = __float22half2_rn(make_float2(r[4], r[5]));
            pk[3] = __float22half2_rn(make_float2(r[6], r[7]));
            *reinterpret_cast<float4*>(gout + (size_t)gnode2 * 64 + c0) =
                *reinterpret_cast<float4*>(pk);
        }
    }
}

// ---------------------------- standalone aggregate (layer 4)
__global__ __launch_bounds__(256) void aggregate_kernel(const __half* __restrict__ g,
                                                        const float* __restrict__ dis,
                                                        const int* __restrict__ offsets,
                                                        const int2* __restrict__ pairs,
                                                        __half* __restrict__ aggout, int n) {
    int node = blockIdx.x * 32 + (threadIdx.x >> 3);
    int q = threadIdx.x & 7;
    if (node >= n) return;
    const float4* gt = reinterpret_cast<const float4*>(g);
    float acc[8] = {0.f, 0.f, 0.f, 0.f, 0.f, 0.f, 0.f, 0.f};
    agg_node(gt, pairs, offsets[node], offsets[node + 1], node, q, acc);
    float dn = dis[node];
    __half2 o[4];
    o[0] = __float22half2_rn(make_float2(dn * acc[0], dn * acc[1]));
    o[1] = __float22half2_rn(make_float2(dn * acc[2], dn * acc[3]));
    o[2] = __float22half2_rn(make_float2(dn * acc[4], dn * acc[5]));
    o[3] = __float22half2_rn(make_float2(dn * acc[6], dn * acc[7]));
    reinterpret_cast<float4*>(aggout)[(size_t)node * 8 + q] = *reinterpret_cast<float4*>(o);
}

// ------------------------------- GEMM 64x40 (fdot2) + bias + row log_softmax -> d_out
__global__ __launch_bounds__(256) void gemm40_softmax_kernel(const __half* __restrict__ in,
                                                             const float* __restrict__ W,
                                                             const float* __restrict__ b,
                                                             float* __restrict__ out, int n) {
    __shared__ __half2 WT[40][32];
    for (int idx = threadIdx.x; idx < 40 * 32; idx += 256) {
        int c = idx % 40, k2 = idx / 40;
        WT[c][k2] = __float22half2_rn(make_float2(W[(2 * k2) * 40 + c],
                                                  W[(2 * k2 + 1) * 40 + c]));
    }
    __syncthreads();

    int row = blockIdx.x * 256 + threadIdx.x;
    if (row >= n) return;

    __half2 h2[32];
    const float4* inp = reinterpret_cast<const float4*>(in + (size_t)row * 64);
    #pragma unroll
    for (int i = 0; i < 8; ++i) {
        float4 raw = inp[i];
        const __half2* hp = reinterpret_cast<const __half2*>(&raw);
        h2[4 * i] = hp[0]; h2[4 * i + 1] = hp[1];
        h2[4 * i + 2] = hp[2]; h2[4 * i + 3] = hp[3];
    }

    float r[40];
    #pragma unroll 2
    for (int c = 0; c < 40; ++c) {
        const __half2* wt = &WT[c][0];
        float a0 = 0.f, a1 = 0.f, a2 = 0.f, a3 = 0.f;
        #pragma unroll
        for (int i = 0; i < 8; ++i) {
            a0 = fdot2f(h2[4 * i],     wt[4 * i],     a0);
            a1 = fdot2f(h2[4 * i + 1], wt[4 * i + 1], a1);
            a2 = fdot2f(h2[4 * i + 2], wt[4 * i + 2], a2);
            a3 = fdot2f(h2[4 * i + 3], wt[4 * i + 3], a3);
        }
        r[c] = (a0 + a1) + (a2 + a3) + b[c];
    }

    float m = r[0];
    #pragma unroll
    for (int c = 1; c < 40; ++c) m = fmaxf(m, r[c]);
    float s = 0.f;
    #pragma unroll
    for (int c = 0; c < 40; ++c) s += expf(r[c] - m);
    float ls = logf(s) + m;

    float* outp = out + (size_t)row * 40;
    #pragma unroll
    for (int c4 = 0; c4 < 10; ++c4) {
        *reinterpret_cast<float4*>(outp + c4 * 4) =
            make_float4(r[c4 * 4] - ls, r[c4 * 4 + 1] - ls,
                        r[c4 * 4 + 2] - ls, r[c4 * 4 + 3] - ls);
    }
}

// ---------------------------------------------------------------- launch

static inline size_t align_up(size_t x, size_t a) { return (x + a - 1) & ~(a - 1); }

extern "C" void kernel_launch(void* const* d_in, const int* in_sizes, int n_in,
                              void* d_out, int out_size, void* d_ws, size_t ws_size,
                              hipStream_t stream) {
    const float* x  = (const float*)d_in[0];
    const int*   ei = (const int*)d_in[1];     // [2][E] flat: src then dst
    const float* ea = (const float*)d_in[2];
    const float* W1 = (const float*)d_in[3];
    const float* b1 = (const float*)d_in[4];
    const float* W2 = (const float*)d_in[5];
    const float* b2 = (const float*)d_in[6];
    const float* W3 = (const float*)d_in[7];
    const float* b3 = (const float*)d_in[8];
    const float* W4 = (const float*)d_in[9];
    const float* b4 = (const float*)d_in[10];

    const int N = in_sizes[0] / 64;
    const int E = in_sizes[1] / 2;

    const int* src = ei;
    const int* dst = ei + E;

    const int nbuck   = (N + NPB - 1) >> NPB_SHIFT;      // 196 for N=100K (<=256)
    const int nblk_ac = (E + CHUNK - 1) / CHUNK;         // 293

    // workspace carve-up
    char* p = (char*)d_ws;
    int*    offsets     = (int*)p;  p += align_up(((size_t)N + 1) * 4, 256);
    int*    bucket_cnt  = (int*)p;  p += align_up(((size_t)nbuck + 1) * 4, 256);
    int*    bucket_base = (int*)p;  p += align_up(((size_t)nbuck + 1) * 4, 256);
    int*    blockbase   = (int*)p;  p += align_up((size_t)nblk_ac * nbuck * 4, 256);
    float*  dis         = (float*)p; p += align_up((size_t)N * 4, 256);
    int2*   pairs       = (int2*)p;  p += align_up(((size_t)E + 8) * 8, 256);
    int2*   temp        = (int2*)p;  p += align_up(((size_t)E + 8) * 8, 256);
    __half* gA          = (__half*)p; p += align_up((size_t)N * 64 * 2, 256);
    __half* gB          = (__half*)p; p += align_up((size_t)N * 64 * 2, 256);
    (void)ws_size;

    const int nb_n   = (N + 255) / 256;
    const int nb_g16 = (N + 15) / 16;
    const int nb_f   = (N + 31) / 32;

    // --- CSR build (two-level counting sort, LDS-privatized) ---
    bucket_init_kernel<<<1, 256, 0, stream>>>(bucket_cnt, nbuck);
    bucket_count_kernel<<<nblk_ac, 256, 0, stream>>>(dst, bucket_cnt, blockbase, nbuck, E);
    bucket_scan_kernel<<<1, 64, 0, stream>>>(bucket_cnt, bucket_base, nbuck, E);
    bucket_scatter_kernel<<<nblk_ac, 256, 0, stream>>>(src, dst, ea, bucket_base,
                                                       blockbase, temp, nbuck, E);
    bucket_csr_kernel<<<nbuck, 256, 0, stream>>>(temp, bucket_base, offsets, pairs, N, E);
    rowsum_scale_kernel<<<nb_g16, 256, 0, stream>>>(offsets, pairs, x, dis, gA, N);

    // --- layers 1..3 fused (aggregate -> GEMM64+ELU -> fp16) ---
    layer_fused_kernel<<<nb_f, 256, 0, stream>>>(gA, dis, offsets, pairs, W1, b1, gB, N);
    layer_fused_kernel<<<nb_f, 256, 0, stream>>>(gB, dis, offsets, pairs, W2, b2, gA, N);
    layer_fused_kernel<<<nb_f, 256, 0, stream>>>(gA, dis, offsets, pairs, W3, b3, gB, N);

    // --- layer 4: aggregate then GEMM40 + log_softmax -> d_out ---
    aggregate_kernel<<<nb_f, 256, 0, stream>>>(gB, dis, offsets, pairs, gA, N);
    gemm40_softmax_kernel<<<nb_n, 256, 0, stream>>>(gA, W4, b4, (float*)d_out, N);
}

// Round 13
// 207.665 us; speedup vs baseline: 1.7827x; 1.0730x over previous
//
#include <hip/hip_runtime.h>
#include <hip/hip_fp16.h>
#include <cstdint>
#include <cmath>

// GCN, 4 layers. Structure: A(hW) = (Ah)W with norm folded into features:
//   g = dis (.) h  stored FP16,
//   A_norm h [d] = dis[d] * ( sum_e w_e * g[src_e] + g[d] )
// CSR via two-level LDS counting sort (R12-proven, ~20us, no atomic wall).
//
// R13: layer kernels rebuilt wave-autonomous. R12 evidence: Occupancy 52%
// (block barrier waits on slowest of 32 Poisson(12) nodes), 6.2M LDS bank
// conflicts (WT[64][32]: every slice reads bank i&31). Changes:
//  (1) each wave aggregates ITS 8 nodes -> LDS, wave-local fence
//      (s_waitcnt lgkmcnt(0) + wave_barrier, no __syncthreads), then GEMMs
//      the same 8 nodes. Imbalance domain 32 -> 8 nodes; waves independent.
//  (2) WT padded to stride 33 -> conflict-free weight reads.
//  (3) layer 4 fully fused: aggregate -> GEMM40 -> log_softmax -> d_out
//      (8 slices x 5 classes; softmax reduce over stride-8 lanes).

#define NPB_SHIFT 9
#define NPB 512              // nodes per bucket
#define CHUNK 4096           // edges per block in count/scatter passes

// ---- fdot2: 2x f16 MAC with fp32 accumulator (guarded builtin)
__device__ __forceinline__ float fdot2f(__half2 a, __half2 b, float c) {
#if defined(__has_builtin)
#if __has_builtin(__builtin_amdgcn_fdot2)
    typedef _Float16 h2v __attribute__((ext_vector_type(2)));
    return __builtin_amdgcn_fdot2(__builtin_bit_cast(h2v, a),
                                  __builtin_bit_cast(h2v, b), c, false);
#else
    float2 fa = __half22float2(a), fb = __half22float2(b);
    return fmaf(fa.x, fb.x, fmaf(fa.y, fb.y, c));
#endif
#else
    float2 fa = __half22float2(a), fb = __half22float2(b);
    return fmaf(fa.x, fb.x, fmaf(fa.y, fb.y, c));
#endif
}

// ---- wave-local LDS fence: all this wave's ds_writes visible to its ds_reads
__device__ __forceinline__ void wave_lds_fence() {
    asm volatile("s_waitcnt lgkmcnt(0)" ::: "memory");
    __builtin_amdgcn_wave_barrier();
    __builtin_amdgcn_sched_barrier(0);
}

// ------------------------------------------- CSR build: two-level counting sort

__global__ __launch_bounds__(256) void bucket_init_kernel(int* __restrict__ bucket_cnt,
                                                          int nbuck) {
    if ((int)threadIdx.x < nbuck) bucket_cnt[threadIdx.x] = 0;
}

__global__ __launch_bounds__(256) void bucket_count_kernel(const int* __restrict__ dst,
                                                           int* __restrict__ bucket_cnt,
                                                           int* __restrict__ blockbase,
                                                           int nbuck, int E) {
    __shared__ int hist[256];
    int tid = threadIdx.x;
    hist[tid] = 0;
    __syncthreads();
    int base = blockIdx.x * CHUNK;
    #pragma unroll
    for (int u = 0; u < CHUNK / 256; ++u) {
        int e = base + u * 256 + tid;
        if (e < E) atomicAdd(&hist[dst[e] >> NPB_SHIFT], 1);
    }
    __syncthreads();
    if (tid < nbuck)
        blockbase[blockIdx.x * nbuck + tid] = atomicAdd(&bucket_cnt[tid], hist[tid]);
}

__global__ __launch_bounds__(64) void bucket_scan_kernel(const int* __restrict__ bucket_cnt,
                                                         int* __restrict__ bucket_base,
                                                         int nbuck, int E) {
    int lane = threadIdx.x;
    int run = 0;
    for (int b0 = 0; b0 < nbuck; b0 += 64) {
        int i = b0 + lane;
        int v = (i < nbuck) ? bucket_cnt[i] : 0;
        int x = v;
        #pragma unroll
        for (int off = 1; off < 64; off <<= 1) {
            int t = __shfl_up(x, off);
            if (lane >= off) x += t;
        }
        if (i < nbuck) bucket_base[i] = run + x - v;
        run += __shfl(x, 63);
    }
    if (lane == 0) bucket_base[nbuck] = E;
}

__global__ __launch_bounds__(256) void bucket_scatter_kernel(const int* __restrict__ src,
                                                             const int* __restrict__ dst,
                                                             const float* __restrict__ w,
                                                             const int* __restrict__ bucket_base,
                                                             const int* __restrict__ blockbase,
                                                             int2* __restrict__ temp,
                                                             int nbuck, int E) {
    __shared__ int cursor[256];
    int tid = threadIdx.x;
    if (tid < nbuck)
        cursor[tid] = bucket_base[tid] + blockbase[blockIdx.x * nbuck + tid];
    __syncthreads();
    int base = blockIdx.x * CHUNK;
    #pragma unroll
    for (int u = 0; u < CHUNK / 256; ++u) {
        int e = base + u * 256 + tid;
        if (e < E) {
            int d = dst[e];
            int pos = atomicAdd(&cursor[d >> NPB_SHIFT], 1);
            temp[pos] = make_int2(src[e] | ((d & (NPB - 1)) << 17),
                                  __float_as_int(w[e]));
        }
    }
}

__global__ __launch_bounds__(256) void bucket_csr_kernel(const int2* __restrict__ temp,
                                                         const int* __restrict__ bucket_base,
                                                         int* __restrict__ offsets,
                                                         int2* __restrict__ pairs,
                                                         int n, int E) {
    __shared__ int cnt[NPB];
    __shared__ int wtot[4];
    int tid = threadIdx.x;
    int bk = blockIdx.x;
    int base = bucket_base[bk], end = bucket_base[bk + 1];
    cnt[tid] = 0; cnt[tid + 256] = 0;
    __syncthreads();
    for (int j = base + tid; j < end; j += 256)
        atomicAdd(&cnt[temp[j].x >> 17], 1);
    __syncthreads();
    int a0 = cnt[2 * tid], a1 = cnt[2 * tid + 1];
    int s = a0 + a1;
    int lane = tid & 63, wid = tid >> 6;
    int x = s;
    #pragma unroll
    for (int off = 1; off < 64; off <<= 1) {
        int t2 = __shfl_up(x, off);
        if (lane >= off) x += t2;
    }
    if (lane == 63) wtot[wid] = x;
    __syncthreads();
    int wbase = 0;
    #pragma unroll
    for (int wv = 0; wv < 4; ++wv) if (wv < wid) wbase += wtot[wv];
    int e0 = wbase + x - s;
    int abs0 = base + e0, abs1 = base + e0 + a0;
    int node0 = bk * NPB + 2 * tid;
    if (node0 < n)     offsets[node0]     = abs0;
    if (node0 + 1 < n) offsets[node0 + 1] = abs1;
    __syncthreads();
    cnt[2 * tid] = abs0; cnt[2 * tid + 1] = abs1;
    __syncthreads();
    for (int j = base + tid; j < end; j += 256) {
        int2 t2 = temp[j];
        int pos = atomicAdd(&cnt[t2.x >> 17], 1);
        pairs[pos] = make_int2(t2.x & 0x1FFFF, t2.y);
    }
    if (bk == 0 && tid == 0) offsets[n] = E;
}

// fused: deg row-sum -> dis -> g0 = fp16(dis (.) x). 16 lanes per node.
__global__ __launch_bounds__(256) void rowsum_scale_kernel(const int* __restrict__ offsets,
                                                           const int2* __restrict__ pairs,
                                                           const float* __restrict__ x,
                                                           float* __restrict__ dis,
                                                           __half* __restrict__ g, int n) {
    int node = blockIdx.x * 16 + (threadIdx.x >> 4);
    int q = threadIdx.x & 15;
    if (node >= n) return;
    int j0 = offsets[node], end = offsets[node + 1];
    float s = 0.f;
    for (int j = j0 + q; j < end; j += 16) s += __int_as_float(pairs[j].y);
    #pragma unroll
    for (int off = 8; off; off >>= 1) s += __shfl_xor(s, off);
    float dn = rsqrtf(1.0f + s);
    if (q == 0) dis[node] = dn;
    float4 v = reinterpret_cast<const float4*>(x)[(size_t)node * 16 + q];
    __half2 pk[2];
    pk[0] = __float22half2_rn(make_float2(dn * v.x, dn * v.y));
    pk[1] = __float22half2_rn(make_float2(dn * v.z, dn * v.w));
    reinterpret_cast<float2*>(g + (size_t)node * 64)[q] = *reinterpret_cast<float2*>(pk);
}

// ---------------------------------------------------------------- aggregation core
__device__ __forceinline__ void accum8(float* acc, float4 rv, float w) {
    const __half2* h = reinterpret_cast<const __half2*>(&rv);
    #pragma unroll
    for (int k = 0; k < 4; ++k) {
        float2 f = __half22float2(h[k]);
        acc[2 * k]     = fmaf(w, f.x, acc[2 * k]);
        acc[2 * k + 1] = fmaf(w, f.y, acc[2 * k + 1]);
    }
}

__device__ __forceinline__ void agg_node(const float4* __restrict__ gt,
                                         const int2* __restrict__ pairs,
                                         int j, int end, int node, int q,
                                         float* __restrict__ acc) {
    for (; j + 4 <= end; j += 4) {
        int2 p0 = pairs[j], p1 = pairs[j + 1], p2 = pairs[j + 2], p3 = pairs[j + 3];
        float4 r0 = gt[(size_t)p0.x * 8 + q];
        float4 r1 = gt[(size_t)p1.x * 8 + q];
        float4 r2 = gt[(size_t)p2.x * 8 + q];
        float4 r3 = gt[(size_t)p3.x * 8 + q];
        accum8(acc, r0, __int_as_float(p0.y));
        accum8(acc, r1, __int_as_float(p1.y));
        accum8(acc, r2, __int_as_float(p2.y));
        accum8(acc, r3, __int_as_float(p3.y));
    }
    for (; j < end; ++j) {
        int2 p = pairs[j];
        float4 r = gt[(size_t)p.x * 8 + q];
        accum8(acc, r, __int_as_float(p.y));
    }
    float4 rs = gt[(size_t)node * 8 + q];   // self term, weight 1
    accum8(acc, rs, 1.0f);
}

// ---- phase 1 (shared by both fused kernels): wave's 8-lane group aggregates
// one node into rows[ln][.] (scaled by dis); no block barrier needed after.
__device__ __forceinline__ void phase1_agg(const __half* __restrict__ gin,
                                           const float* __restrict__ dis,
                                           const int* __restrict__ offsets,
                                           const int2* __restrict__ pairs,
                                           __half2 (*rows)[33], int n, int tid,
                                           int blockbase_node) {
    int ln = tid >> 3;
    int q  = tid & 7;
    int gnode = blockbase_node + ln;
    if (gnode < n) {
        const float4* gt = reinterpret_cast<const float4*>(gin);
        float acc[8] = {0.f, 0.f, 0.f, 0.f, 0.f, 0.f, 0.f, 0.f};
        agg_node(gt, pairs, offsets[gnode], offsets[gnode + 1], gnode, q, acc);
        float dn = dis[gnode];
        #pragma unroll
        for (int k2 = 0; k2 < 4; ++k2)
            rows[ln][q * 4 + k2] =
                __float22half2_rn(make_float2(dn * acc[2 * k2], dn * acc[2 * k2 + 1]));
    }
}

// -------------------------------- fused layer 1-3: aggregate -> GEMM64+ELU -> fp16
// Wave-autonomous: wave w aggregates nodes 8w..8w+7, wave-fence, then GEMMs them
// (lane = node(lane&7) x slice(lane>>3), 8 outputs per thread). WT stride 33.
__global__ __launch_bounds__(256) void layer_fused_kernel(const __half* __restrict__ gin,
                                                          const float* __restrict__ dis,
                                                          const int* __restrict__ offsets,
                                                          const int2* __restrict__ pairs,
                                                          const float* __restrict__ W,
                                                          const float* __restrict__ b,
                                                          __half* __restrict__ gout, int n) {
    __shared__ __half2 rows[32][33];
    __shared__ __half2 WT[64][33];   // WT[c][k2] = (W[2k2][c], W[2k2+1][c]) fp16
    __shared__ float bias_s[64];
    for (int idx = threadIdx.x; idx < 64 * 32; idx += 256) {
        int k2 = idx >> 6, c = idx & 63;
        WT[c][k2] = __float22half2_rn(make_float2(W[(2 * k2) * 64 + c],
                                                  W[(2 * k2 + 1) * 64 + c]));
    }
    if (threadIdx.x < 64) bias_s[threadIdx.x] = b[threadIdx.x];
    __syncthreads();          // WT/bias ready (only block barrier)

    int tid = threadIdx.x;
    phase1_agg(gin, dis, offsets, pairs, rows, n, tid, blockIdx.x * 32);
    wave_lds_fence();         // this wave's rows visible to this wave

    int lane  = tid & 63, wave = tid >> 6;
    int node2 = wave * 8 + (lane & 7);
    int slice = lane >> 3;                 // 0..7 -> outputs [8*slice, 8*slice+8)
    int gnode2 = blockIdx.x * 32 + node2;
    if (gnode2 < n) {
        __half2 h2[32];
        #pragma unroll
        for (int i = 0; i < 32; ++i) h2[i] = rows[node2][i];
        float dn = dis[gnode2];
        int c0 = slice * 8;
        float r[8];
        #pragma unroll
        for (int cc = 0; cc < 8; ++cc) {
            const __half2* wt = &WT[c0 + cc][0];
            float a0 = 0.f, a1 = 0.f, a2 = 0.f, a3 = 0.f;
            #pragma unroll
            for (int i = 0; i < 8; ++i) {
                a0 = fdot2f(h2[4 * i],     wt[4 * i],     a0);
                a1 = fdot2f(h2[4 * i + 1], wt[4 * i + 1], a1);
                a2 = fdot2f(h2[4 * i + 2], wt[4 * i + 2], a2);
                a3 = fdot2f(h2[4 * i + 3], wt[4 * i + 3], a3);
            }
            float v = (a0 + a1) + (a2 + a3) + bias_s[c0 + cc];
            v = (v > 0.f) ? v : expm1f(v);          // ELU
            r[cc] = dn * v;                          // pre-scale for next layer
        }
        __half2 pk[4];
        pk[0] = __float22half2_rn(make_float2(r[0], r[1]));
        pk[1] = __float22half2_rn(make_float2(r[2], r[3]));
        pk[2] = __float22half2_rn(make_float2(r[4], r[5]));
        pk[3] = __float22half2_rn(make_float2(r[6], r[7]));
        *reinterpret_cast<float4*>(gout + (size_t)gnode2 * 64 + c0) =
            *reinterpret_cast<float4*>(pk);
    }
}

// ------------- fused layer 4: aggregate -> GEMM40 -> log_softmax -> d_out
// Phase 2: lane = node(lane&7) x slice(lane>>3); slice covers 5 classes
// (8x5 = 40, all lanes active). Softmax reduce over stride-8 lane group.
__global__ __launch_bounds__(256) void layer4_fused_kernel(const __half* __restrict__ gin,
                                                           const float* __restrict__ dis,
                                                           const int* __restrict__ offsets,
                                                           const int2* __restrict__ pairs,
                                                           const float* __restrict__ W,
                                                           const float* __restrict__ b,
                                                           float* __restrict__ out, int n) {
    __shared__ __half2 rows[32][33];
    __shared__ __half2 WT[40][33];   // WT[c][k2] = (W[2k2][c], W[2k2+1][c]) fp16
    __shared__ float bias_s[40];
    for (int idx = threadIdx.x; idx < 40 * 32; idx += 256) {
        int c = idx % 40, k2 = idx / 40;
        WT[c][k2] = __float22half2_rn(make_float2(W[(2 * k2) * 40 + c],
                                                  W[(2 * k2 + 1) * 40 + c]));
    }
    if (threadIdx.x < 40) bias_s[threadIdx.x] = b[threadIdx.x];
    __syncthreads();

    int tid = threadIdx.x;
    phase1_agg(gin, dis, offsets, pairs, rows, n, tid, blockIdx.x * 32);
    wave_lds_fence();

    int lane  = tid & 63, wave = tid >> 6;
    int node2 = wave * 8 + (lane & 7);
    int slice = lane >> 3;                 // 0..7 -> classes [5*slice, 5*slice+5)
    int gnode2 = blockIdx.x * 32 + node2;

    float r[5];
    float mp = -__builtin_inff();
    if (gnode2 < n) {
        __half2 h2[32];
        #pragma unroll
        for (int i = 0; i < 32; ++i) h2[i] = rows[node2][i];
        int c0 = slice * 5;
        #pragma unroll
        for (int cc = 0; cc < 5; ++cc) {
            const __half2* wt = &WT[c0 + cc][0];
            float a0 = 0.f, a1 = 0.f, a2 = 0.f, a3 = 0.f;
            #pragma unroll
            for (int i = 0; i < 8; ++i) {
                a0 = fdot2f(h2[4 * i],     wt[4 * i],     a0);
                a1 = fdot2f(h2[4 * i + 1], wt[4 * i + 1], a1);
                a2 = fdot2f(h2[4 * i + 2], wt[4 * i + 2], a2);
                a3 = fdot2f(h2[4 * i + 3], wt[4 * i + 3], a3);
            }
            r[cc] = (a0 + a1) + (a2 + a3) + bias_s[c0 + cc];
            mp = fmaxf(mp, r[cc]);
        }
    }
    // row max over the 8 slices (lanes node2, node2+8, ..., node2+56)
    mp = fmaxf(mp, __shfl_xor(mp, 8));
    mp = fmaxf(mp, __shfl_xor(mp, 16));
    mp = fmaxf(mp, __shfl_xor(mp, 32));
    float sp = 0.f;
    if (gnode2 < n) {
        #pragma unroll
        for (int cc = 0; cc < 5; ++cc) sp += expf(r[cc] - mp);
    }
    sp += __shfl_xor(sp, 8);
    sp += __shfl_xor(sp, 16);
    sp += __shfl_xor(sp, 32);
    if (gnode2 < n) {
        float ls = logf(sp) + mp;
        float* outp = out + (size_t)gnode2 * 40 + slice * 5;
        #pragma unroll
        for (int cc = 0; cc < 5; ++cc) outp[cc] = r[cc] - ls;
    }
}

// ---------------------------------------------------------------- launch

static inline size_t align_up(size_t x, size_t a) { return (x + a - 1) & ~(a - 1); }

extern "C" void kernel_launch(void* const* d_in, const int* in_sizes, int n_in,
                              void* d_out, int out_size, void* d_ws, size_t ws_size,
                              hipStream_t stream) {
    const float* x  = (const float*)d_in[0];
    const int*   ei = (const int*)d_in[1];     // [2][E] flat: src then dst
    const float* ea = (const float*)d_in[2];
    const float* W1 = (const float*)d_in[3];
    const float* b1 = (const float*)d_in[4];
    const float* W2 = (const float*)d_in[5];
    const float* b2 = (const float*)d_in[6];
    const float* W3 = (const float*)d_in[7];
    const float* b3 = (const float*)d_in[8];
    const float* W4 = (const float*)d_in[9];
    const float* b4 = (const float*)d_in[10];

    const int N = in_sizes[0] / 64;
    const int E = in_sizes[1] / 2;

    const int* src = ei;
    const int* dst = ei + E;

    const int nbuck   = (N + NPB - 1) >> NPB_SHIFT;      // 196 for N=100K (<=256)
    const int nblk_ac = (E + CHUNK - 1) / CHUNK;         // 293

    // workspace carve-up
    char* p = (char*)d_ws;
    int*    offsets     = (int*)p;  p += align_up(((size_t)N + 1) * 4, 256);
    int*    bucket_cnt  = (int*)p;  p += align_up(((size_t)nbuck + 1) * 4, 256);
    int*    bucket_base = (int*)p;  p += align_up(((size_t)nbuck + 1) * 4, 256);
    int*    blockbase   = (int*)p;  p += align_up((size_t)nblk_ac * nbuck * 4, 256);
    float*  dis         = (float*)p; p += align_up((size_t)N * 4, 256);
    int2*   pairs       = (int2*)p;  p += align_up(((size_t)E + 8) * 8, 256);
    int2*   temp        = (int2*)p;  p += align_up(((size_t)E + 8) * 8, 256);
    __half* gA          = (__half*)p; p += align_up((size_t)N * 64 * 2, 256);
    __half* gB          = (__half*)p; p += align_up((size_t)N * 64 * 2, 256);
    (void)ws_size;

    const int nb_g16 = (N + 15) / 16;
    const int nb_f   = (N + 31) / 32;

    // --- CSR build (two-level counting sort, LDS-privatized) ---
    bucket_init_kernel<<<1, 256, 0, stream>>>(bucket_cnt, nbuck);
    bucket_count_kernel<<<nblk_ac, 256, 0, stream>>>(dst, bucket_cnt, blockbase, nbuck, E);
    bucket_scan_kernel<<<1, 64, 0, stream>>>(bucket_cnt, bucket_base, nbuck, E);
    bucket_scatter_kernel<<<nblk_ac, 256, 0, stream>>>(src, dst, ea, bucket_base,
                                                       blockbase, temp, nbuck, E);
    bucket_csr_kernel<<<nbuck, 256, 0, stream>>>(temp, bucket_base, offsets, pairs, N, E);
    rowsum_scale_kernel<<<nb_g16, 256, 0, stream>>>(offsets, pairs, x, dis, gA, N);

    // --- layers 1..3 fused (aggregate -> GEMM64+ELU -> fp16), wave-autonomous ---
    layer_fused_kernel<<<nb_f, 256, 0, stream>>>(gA, dis, offsets, pairs, W1, b1, gB, N);
    layer_fused_kernel<<<nb_f, 256, 0, stream>>>(gB, dis, offsets, pairs, W2, b2, gA, N);
    layer_fused_kernel<<<nb_f, 256, 0, stream>>>(gA, dis, offsets, pairs, W3, b3, gB, N);

    // --- layer 4 fused: aggregate -> GEMM40 -> log_softmax -> d_out ---
    layer4_fused_kernel<<<nb_f, 256, 0, stream>>>(gB, dis, offsets, pairs, W4, b4,
                                                  (float*)d_out, N);
}